// Round 14
// baseline (278.774 us; speedup 1.0000x reference)
//
#include <hip/hip_runtime.h>
#include <math.h>

constexpr int Bc = 2, Nseq = 1024, Dh = 512, Nh = 16, Dhead = 32;
constexpr float FACT = 0.08838834764831845f; // 0.5/sqrt(32)
constexpr float LOG2E = 1.4426950408889634f;

typedef __attribute__((ext_vector_type(8))) __bf16 bf16x8;
typedef __attribute__((ext_vector_type(4))) float f32x4;

__device__ __forceinline__ short f2b(float x) {
    union { float f; unsigned u; } v; v.f = x;
    unsigned r = v.u + 0x7fffu + ((v.u >> 16) & 1u);
    return (short)(r >> 16);
}
__device__ __forceinline__ float b2f(short s) {
    union { unsigned u; float f; } v; v.u = ((unsigned)(unsigned short)s) << 16;
    return v.f;
}

#define GL2LDS(g, s) __builtin_amdgcn_global_load_lds(                  \
    (const void __attribute__((address_space(1)))*)(g),                 \
    (void __attribute__((address_space(3)))*)(s), 16, 0, 0)

// ---- shared 128x128-tile bf16 MFMA mainloop (async GL2LDS staging) ----
__device__ __forceinline__ void mfma_loop(const short* __restrict__ A, int lda,
                                          const short* __restrict__ B, int ldb,
                                          int K, short* __restrict__ smA,
                                          short* __restrict__ smB, f32x4 acc[4][4]) {
    const int tid = threadIdx.x;
    const int lane = tid & 63;
    const int w = tid >> 6;
    const int wr = (w >> 1) * 64, wc = (w & 1) * 64;
    const int lr = lane & 15;
    const int srow = tid >> 3;   // 0..31
    const int scol = tid & 7;    // 16B chunk 0..7
    for (int k0 = 0; k0 < K; k0 += 64) {
        __syncthreads();  // prior iteration's LDS reads complete
#pragma unroll
        for (int r = 0; r < 4; r++) {
            int row = r * 32 + srow;
            int gc = scol ^ (row & 7);  // pre-swizzled source
            GL2LDS(A + (long)row * lda + k0 + gc * 8, smA + row * 64 + scol * 8);
            GL2LDS(B + (long)row * ldb + k0 + gc * 8, smB + row * 64 + scol * 8);
        }
        __syncthreads();  // vmcnt(0) drain -> tiles visible
#pragma unroll
        for (int h = 0; h < 2; h++) {
            int cb = h * 4 + (lane >> 4);
            bf16x8 af[4], bv[4];
#pragma unroll
            for (int i = 0; i < 4; i++) {
                int row = wr + i * 16 + lr;
                af[i] = *(const bf16x8*)(smA + row * 64 + ((cb ^ (row & 7)) << 3));
            }
#pragma unroll
            for (int j = 0; j < 4; j++) {
                int row = wc + j * 16 + lr;
                bv[j] = *(const bf16x8*)(smB + row * 64 + ((cb ^ (row & 7)) << 3));
            }
            __builtin_amdgcn_s_setprio(1);
#pragma unroll
            for (int i = 0; i < 4; i++)
#pragma unroll
                for (int j = 0; j < 4; j++)
                    acc[i][j] = __builtin_amdgcn_mfma_f32_16x16x32_bf16(af[i], bv[j], acc[i][j], 0, 0, 0);
            __builtin_amdgcn_s_setprio(0);
        }
    }
}

// flags: 1 = silu, 2 = output bf16; aux != null -> also store bf16 copy to aux
__global__ __launch_bounds__(256) void gemm_bf16(
    const short* __restrict__ A, int lda, long sAz,
    const short* __restrict__ B, int ldb, long sBz,
    void* __restrict__ C, int ldc, long sCz,
    const float* __restrict__ bias,
    const float* __restrict__ resid, int ldr, long sRz,
    short* __restrict__ aux,
    int K, int flags)
{
    __shared__ short smA[128 * 64], smB[128 * 64];
    const long z = blockIdx.z;
    const short* Ab = A + z * sAz + (long)blockIdx.y * 128 * lda;
    const short* Bb = B + z * sBz + (long)blockIdx.x * 128 * ldb;
    f32x4 acc[4][4] = {};
    mfma_loop(Ab, lda, Bb, ldb, K, smA, smB, acc);
    const int tid = threadIdx.x, lane = tid & 63, w = tid >> 6;
    const int wr = (w >> 1) * 64, wc = (w & 1) * 64, lr = lane & 15, r0 = (lane >> 4) * 4;
    const int m0 = blockIdx.y * 128, n0 = blockIdx.x * 128;
    float* Cf = (float*)C; short* Cs = (short*)C;
    const float* rz = resid ? resid + z * sRz : nullptr;
#pragma unroll
    for (int i = 0; i < 4; i++)
#pragma unroll
        for (int j = 0; j < 4; j++) {
            int col = n0 + wc + j * 16 + lr;
            float bv = bias ? bias[col] : 0.f;
#pragma unroll
            for (int q = 0; q < 4; q++) {
                int row = m0 + wr + i * 16 + r0 + q;
                float c = acc[i][j][q] + bv;
                if (rz) c += rz[(long)row * ldr + col];
                if (flags & 1) c = c / (1.f + __expf(-c));
                long off = z * sCz + (long)row * ldc + col;
                if (flags & 2) Cs[off] = f2b(c); else Cf[off] = c;
                if (aux) aux[off] = f2b(c);
            }
        }
}

// ---- merged QKV + Vvv projections in one dispatch ----
__global__ __launch_bounds__(256) void gemm_qkv_vvv(
    const short* __restrict__ Hn, const short* __restrict__ WqkvT,
    const short* __restrict__ Vbf, const short* __restrict__ WvvT,
    short* __restrict__ Hqkv, short* __restrict__ VvR,
    const float* __restrict__ bqkv)
{
    __shared__ short smA[128 * 64], smB[128 * 64];
    const bool qkv = blockIdx.y < 16;
    if (!qkv && blockIdx.x >= 4) return;
    const int yy = qkv ? blockIdx.y : blockIdx.y - 16;
    const short* Ab = (qkv ? Hn : Vbf) + (long)yy * 128 * 512;
    const short* Bb = (qkv ? WqkvT : WvvT) + (long)blockIdx.x * 128 * 512;
    f32x4 acc[4][4] = {};
    mfma_loop(Ab, 512, Bb, 512, 512, smA, smB, acc);
    const int tid = threadIdx.x, lane = tid & 63, w = tid >> 6;
    const int wr = (w >> 1) * 64, wc = (w & 1) * 64, lr = lane & 15, r0 = (lane >> 4) * 4;
    const int m0 = yy * 128, n0 = blockIdx.x * 128;
    short* Cs = qkv ? Hqkv : VvR;
    const int ldc = qkv ? 4608 : 512;
#pragma unroll
    for (int i = 0; i < 4; i++)
#pragma unroll
        for (int j = 0; j < 4; j++) {
            int col = n0 + wc + j * 16 + lr;
            float bv = qkv ? bqkv[col] : 0.f;
#pragma unroll
            for (int q = 0; q < 4; q++) {
                int row = m0 + wr + i * 16 + r0 + q;
                Cs[(long)row * ldc + col] = f2b(acc[i][j][q] + bv);
            }
        }
}

// ---- merged Wo + Wvo output projections (A = [Hres|Vres] contiguous) ----
__global__ __launch_bounds__(256) void gemm_out(
    const short* __restrict__ Ares, const short* __restrict__ WoT,
    const short* __restrict__ WvoT, float* __restrict__ outHV,
    const float* __restrict__ H, const float* __restrict__ V,
    short* __restrict__ Vbf2, const float* __restrict__ bo)
{
    __shared__ short smA[128 * 64], smB[128 * 64];
    const bool isH = blockIdx.y < 16;
    const short* Ab = Ares + (long)blockIdx.y * 128 * 512;
    const short* Bb = (isH ? WoT : WvoT) + (long)blockIdx.x * 128 * 512;
    f32x4 acc[4][4] = {};
    mfma_loop(Ab, 512, Bb, 512, 512, smA, smB, acc);
    const int tid = threadIdx.x, lane = tid & 63, w = tid >> 6;
    const int wr = (w >> 1) * 64, wc = (w & 1) * 64, lr = lane & 15, r0 = (lane >> 4) * 4;
    const int m0 = blockIdx.y * 128, n0 = blockIdx.x * 128;
#pragma unroll
    for (int i = 0; i < 4; i++)
#pragma unroll
        for (int j = 0; j < 4; j++) {
            int col = n0 + wc + j * 16 + lr;
            float bv = isH ? bo[col] : 0.f;
#pragma unroll
            for (int q = 0; q < 4; q++) {
                int row = m0 + wr + i * 16 + r0 + q;
                float c = acc[i][j][q] + bv;
                if (isH) c += H[(long)row * 512 + col];
                else     c += V[(long)(row - 2048) * 512 + col];
                outHV[(long)row * 512 + col] = c;
                if (!isH) Vbf2[(long)(row - 2048) * 512 + col] = f2b(c);
            }
        }
}

// ---- W2 GEMM with fused final update: outH += s[:,:512]; outV += s[:,512:]*V2 ----
__global__ __launch_bounds__(256) void gemm_w2f(
    const short* __restrict__ t1, const short* __restrict__ W2T,
    const float* __restrict__ b2, float* __restrict__ outH,
    float* __restrict__ outV, const short* __restrict__ VpB)
{
    __shared__ short smA[128 * 64], smB[128 * 64];
    const short* Ab = t1 + (long)blockIdx.y * 128 * 2048;
    const short* Bb = W2T + (long)blockIdx.x * 128 * 2048;
    f32x4 acc[4][4] = {};
    mfma_loop(Ab, 2048, Bb, 2048, 2048, smA, smB, acc);
    const int tid = threadIdx.x, lane = tid & 63, w = tid >> 6;
    const int wr = (w >> 1) * 64, wc = (w & 1) * 64, lr = lane & 15, r0 = (lane >> 4) * 4;
    const int m0 = blockIdx.y * 128, n0 = blockIdx.x * 128;
#pragma unroll
    for (int i = 0; i < 4; i++)
#pragma unroll
        for (int j = 0; j < 4; j++) {
            int col = n0 + wc + j * 16 + lr;
            float bv = b2[col];
#pragma unroll
            for (int q = 0; q < 4; q++) {
                int row = m0 + wr + i * 16 + r0 + q;
                float val = acc[i][j][q] + bv;
                if (col < 512) {
                    outH[(long)row * 512 + col] += val;
                } else {
                    int cc = col - 512;
#pragma unroll
                    for (int c = 0; c < 3; c++) {
                        long r3 = (long)row * 3 + c;
                        float v2 = b2f(VpB[r3 * 1024 + 512 + cc]);
                        outV[r3 * 512 + cc] += val * v2;
                    }
                }
            }
        }
}

// ---- fused flash attention v9: 256 thr, 4 warps x 16 q-rows, QBLK=64,
// KVBLK=64 -> 40KB LDS -> 4 blocks/CU (16 waves). Register-staged K/V,
// warp-private bias/P, 2 barriers/iter, log2 softmax + deferred rescale,
// XCD-aware mapping. 16 kv-iterations. ----
__global__ __launch_bounds__(256, 2) void flash_attn(
    const short* __restrict__ Hq, const short* __restrict__ Hk,
    const short* __restrict__ VaT, const float* __restrict__ rbf,
    const float* __restrict__ Dm, const float* __restrict__ maskadd,
    short* __restrict__ Hres, short* __restrict__ Vres, int ldq)
{
    __shared__ short smK[64 * 128];    // [kv][d]   16KB
    __shared__ short smV[128 * 64];    // [d][kv]   16KB
    __shared__ short smP[4 * 16 * 64]; // per-warp bias->P, 8KB
    const int xcd = blockIdx.x & 7, idx = blockIdx.x >> 3;
    const int s = (idx >> 4) * 8 + xcd;
    const int qt = idx & 15;
    const int b = s >> 4, h = s & 15;
    const int q0 = qt * 64;
    const int tid = threadIdx.x, lane = tid & 63, w = tid >> 6;
    const int lr = lane & 15, hi = lane >> 4, r0 = hi * 4;
    const int c16 = tid & 15, rS = tid >> 4;   // K staging
    const int c8 = tid & 7, rS8 = tid >> 3;    // V staging
    short* smPw = smP + w * 1024;

    bf16x8 qf[4];
    {
        const short* qb = Hq + ((long)b * Nseq + q0 + w * 16 + lr) * ldq + h * 128 + hi * 8;
#pragma unroll
        for (int kk = 0; kk < 4; kk++) qf[kk] = *(const bf16x8*)(qb + kk * 32);
    }

    f32x4 oac[8] = {};
    float ml[4], ll[4];
#pragma unroll
    for (int q = 0; q < 4; q++) { ml[q] = -INFINITY; ll[q] = 0.f; }

    const short* Kg = Hk + (long)b * Nseq * ldq + h * 128;
    const short* Vg = VaT + (long)s * 128 * Nseq;
    const float* rbb = rbf + ((long)s * Nseq + q0 + w * 16) * Nseq;
    const float* Dbb = Dm + ((long)b * Nseq + q0 + w * 16) * Nseq;
    const float* mab = maskadd + b * Nseq;
    const int bcol = (lane & 15) * 4, brow = lane >> 4;

    for (int kt = 0; kt < 16; kt++) {
        __syncthreads();  // (1) prior iteration's LDS reads complete
        {
            bf16x8 t8[4];
#pragma unroll
            for (int r = 0; r < 4; r++)
                t8[r] = *(const bf16x8*)(Kg + (long)(kt * 64 + rS + r * 16) * ldq + c16 * 8);
#pragma unroll
            for (int r = 0; r < 4; r++) {
                int row = rS + r * 16;
                *(bf16x8*)(smK + row * 128 + ((c16 ^ (row & 15)) << 3)) = t8[r];
            }
#pragma unroll
            for (int r = 0; r < 4; r++)
                t8[r] = *(const bf16x8*)(Vg + (long)(rS8 + r * 32) * Nseq + kt * 64 + c8 * 8);
#pragma unroll
            for (int r = 0; r < 4; r++) {
                int row = rS8 + r * 32;
                *(bf16x8*)(smV + row * 64 + ((c8 ^ (row & 7)) << 3)) = t8[r];
            }
        }
        {
            short4 hb[4];
            float4 mk = *(const float4*)(mab + kt * 64 + bcol);
#pragma unroll
            for (int it = 0; it < 4; it++) {
                int row = it * 4 + brow;
                float4 rv = *(const float4*)(rbb + (long)row * Nseq + kt * 64 + bcol);
                float4 dv = *(const float4*)(Dbb + (long)row * Nseq + kt * 64 + bcol);
                hb[it].x = f2b((rv.x + dv.x + mk.x) * LOG2E);
                hb[it].y = f2b((rv.y + dv.y + mk.y) * LOG2E);
                hb[it].z = f2b((rv.z + dv.z + mk.z) * LOG2E);
                hb[it].w = f2b((rv.w + dv.w + mk.w) * LOG2E);
            }
            int ch = bcol >> 3;
#pragma unroll
            for (int it = 0; it < 4; it++) {
                int row = it * 4 + brow;
                *(short4*)(smPw + row * 64 + ((ch ^ (row & 7)) << 3) + (bcol & 7)) = hb[it];
            }
        }
        __syncthreads();  // (2) K/V/bias staged

        // S = Q @ K^T (log2 domain), 64 kv cols
        f32x4 sac[4] = {};
#pragma unroll
        for (int kk = 0; kk < 4; kk++) {
            int cb = kk * 4 + hi;
            bf16x8 kv8[4];
#pragma unroll
            for (int j = 0; j < 4; j++) {
                int row = j * 16 + lr;
                kv8[j] = *(const bf16x8*)(smK + row * 128 + ((cb ^ (row & 15)) << 3));
            }
#pragma unroll
            for (int j = 0; j < 4; j++)
                sac[j] = __builtin_amdgcn_mfma_f32_16x16x32_bf16(qf[kk], kv8[j], sac[j], 0, 0, 0);
        }
        // bias add (warp-private LDS) + row max
        float tmax[4];
#pragma unroll
        for (int q = 0; q < 4; q++) tmax[q] = -INFINITY;
#pragma unroll
        for (int j = 0; j < 4; j++) {
            int col = j * 16 + lr;
            int ch = col >> 3, in8 = col & 7;
#pragma unroll
            for (int q = 0; q < 4; q++) {
                int row = r0 + q;
                float x = sac[j][q] + b2f(smPw[row * 64 + ((ch ^ (row & 7)) << 3) + in8]);
                sac[j][q] = x;
                tmax[q] = fmaxf(tmax[q], x);
            }
        }
#pragma unroll
        for (int st = 1; st < 16; st <<= 1)
#pragma unroll
            for (int q = 0; q < 4; q++) tmax[q] = fmaxf(tmax[q], __shfl_xor(tmax[q], st));
        // deferred rescale (T13)
        float dm = -INFINITY;
#pragma unroll
        for (int q = 0; q < 4; q++) dm = fmaxf(dm, tmax[q] - ml[q]);
        if (!__all(dm <= 8.f)) {
#pragma unroll
            for (int q = 0; q < 4; q++) {
                float mn = fmaxf(ml[q], tmax[q]);
                float sc = exp2f(ml[q] - mn);
                ml[q] = mn;
                ll[q] *= sc;
#pragma unroll
                for (int j = 0; j < 8; j++) oac[j][q] *= sc;
            }
        }
        float rsum[4] = {0.f, 0.f, 0.f, 0.f};
#pragma unroll
        for (int j = 0; j < 4; j++)
#pragma unroll
            for (int q = 0; q < 4; q++) {
                float p = exp2f(sac[j][q] - ml[q]);
                sac[j][q] = p;
                rsum[q] += p;
            }
#pragma unroll
        for (int st = 1; st < 16; st <<= 1)
#pragma unroll
            for (int q = 0; q < 4; q++) rsum[q] += __shfl_xor(rsum[q], st);
#pragma unroll
        for (int q = 0; q < 4; q++) ll[q] += rsum[q];
        // P -> warp-private LDS (same-warp ordering; no barrier)
#pragma unroll
        for (int j = 0; j < 4; j++) {
            int col = j * 16 + lr;
            int ch = col >> 3, in8 = col & 7;
#pragma unroll
            for (int q = 0; q < 4; q++) {
                int row = r0 + q;
                smPw[row * 64 + ((ch ^ (row & 7)) << 3) + in8] = f2b(sac[j][q]);
            }
        }
        // O += P @ V (kv = 64 -> 2 kk steps)
#pragma unroll
        for (int kk = 0; kk < 2; kk++) {
            int cb = kk * 4 + hi;
            bf16x8 paf = *(const bf16x8*)(smPw + lr * 64 + ((cb ^ (lr & 7)) << 3));
            bf16x8 vv[8];
#pragma unroll
            for (int j = 0; j < 8; j++) {
                int row = j * 16 + lr;
                vv[j] = *(const bf16x8*)(smV + row * 64 + ((cb ^ (row & 7)) << 3));
            }
#pragma unroll
            for (int j = 0; j < 8; j++)
                oac[j] = __builtin_amdgcn_mfma_f32_16x16x32_bf16(paf, vv[j], oac[j], 0, 0, 0);
        }
    }
    // normalize + scatter
    float inv[4];
#pragma unroll
    for (int q = 0; q < 4; q++) inv[q] = 1.f / ll[q];
#pragma unroll
    for (int j = 0; j < 8; j++) {
        int d = j * 16 + lr;
#pragma unroll
        for (int q = 0; q < 4; q++) {
            int n = q0 + w * 16 + r0 + q;
            float o = oac[j][q] * inv[q];
            if (d < 32) Hres[((long)b * Nseq + n) * 512 + h * 32 + d] = f2b(o);
            else {
                int c3 = (d - 32) >> 5, dd = (d - 32) & 31;
                Vres[(((long)b * Nseq + n) * 3 + c3) * 512 + h * 32 + dd] = f2b(o);
            }
        }
    }
}

// ---- merged prep kernel: 9 weight transposes + V convert + bqkv + maskadd ----
struct PrepJobs {
    const float* W[9];
    short* Wt[9];
    int K[9], N[9], nx[9], base[9];
    float scale[9];
    int base_convk, base_bprep, base_mask;
    const float* V; short* Vbf;
    const float* bq; const float* bk; const float* bvs; float* bqkv;
    const int* mask; float* maskadd;
};

__global__ __launch_bounds__(256) void prep_k(PrepJobs a) {
    int bid = blockIdx.x;
    int tid = threadIdx.x;
    if (bid >= a.base_convk) {
        if (bid < a.base_bprep) {
            int i = (bid - a.base_convk) * 256 + tid;
            float4 v = ((const float4*)a.V)[i];
            short4 s;
            s.x = f2b(v.x); s.y = f2b(v.y); s.z = f2b(v.z); s.w = f2b(v.w);
            ((short4*)a.Vbf)[i] = s;
        } else if (bid < a.base_mask) {
            int i = (bid - a.base_bprep) * 256 + tid;
            float v;
            if (i < 2048) v = a.bq[i] * (FACT * LOG2E);
            else if (i < 4096) v = a.bk[i - 2048];
            else v = a.bvs[i - 4096];
            a.bqkv[i] = v;
        } else {
            int i = (bid - a.base_mask) * 256 + tid;
            a.maskadd[i] = a.mask[i] ? 0.f : -1e30f;
        }
        return;
    }
    int j = 0;
#pragma unroll
    for (int t = 1; t < 9; t++) j = (bid >= a.base[t]) ? t : j;
    const float* W = a.W[j];
    short* Wt = a.Wt[j];
    int K = a.K[j], N = a.N[j];
    float scale = a.scale[j];
    int local = bid - a.base[j];
    int nx = a.nx[j];
    int bx = local % nx, by = local / nx;
    __shared__ float t[32][33];
    int n0 = bx * 32, k0 = by * 32;
    int tx = tid & 31, ty = tid >> 5;
#pragma unroll
    for (int r = 0; r < 4; r++) t[ty + r * 8][tx] = W[(long)(k0 + ty + r * 8) * N + n0 + tx];
    __syncthreads();
#pragma unroll
    for (int r = 0; r < 4; r++) Wt[(long)(n0 + ty + r * 8) * K + k0 + tx] = f2b(t[tx][ty + r * 8] * scale);
}

__device__ __forceinline__ void stv(float* p, float v) { *p = v; }
__device__ __forceinline__ void stv(short* p, float v) { *p = f2b(v); }

// LayerNorm, output row stride ldo
template <typename OT>
__global__ __launch_bounds__(256) void ln_kernel(const float* __restrict__ x,
                                                 const float* __restrict__ g,
                                                 const float* __restrict__ b,
                                                 OT* __restrict__ y, int ldo) {
    int row = blockIdx.x;
    const float* xr = x + (long)row * Dh;
    OT* yr = y + (long)row * ldo;
    int tid = threadIdx.x;
    float v0 = xr[tid], v1 = xr[tid + 256];
    __shared__ float red[256];
    red[tid] = v0 + v1;
    __syncthreads();
    for (int o = 128; o > 0; o >>= 1) { if (tid < o) red[tid] += red[tid + o]; __syncthreads(); }
    float mean = red[0] * (1.0f / Dh);
    __syncthreads();
    float d0 = v0 - mean, d1 = v1 - mean;
    red[tid] = d0 * d0 + d1 * d1;
    __syncthreads();
    for (int o = 128; o > 0; o >>= 1) { if (tid < o) red[tid] += red[tid + o]; __syncthreads(); }
    float rstd = rsqrtf(red[0] * (1.0f / Dh) + 1e-5f);
    stv(&yr[tid], d0 * rstd * g[tid] + b[tid]);
    stv(&yr[tid + 256], d1 * rstd * g[tid + 256] + b[tid + 256]);
}

// ---- Vattn_t gather, vectorized ----
__global__ __launch_bounds__(256) void vattn_t8(const short* __restrict__ Hv, int ldh,
                                                const short* __restrict__ Vv,
                                                short* __restrict__ VaT) {
    int idx = blockIdx.x * 256 + threadIdx.x;
    int m = idx & 1023;
    int c = (idx >> 10) & 15;
    int s = idx >> 14;
    int b = s >> 4, h = s & 15;
    bf16x8 v;
    if (c < 4) {
        v = *(const bf16x8*)(Hv + ((long)b * Nseq + m) * ldh + h * 32 + c * 8);
    } else {
        int c3 = (c - 4) >> 2, dd = ((c - 4) & 3) * 8;
        v = *(const bf16x8*)(Vv + (((long)b * Nseq + m) * 3 + c3) * 512 + h * 32 + dd);
    }
    short* out = VaT + (long)s * 128 * 1024 + (long)c * 8 * 1024 + m;
    const short* vs = (const short*)&v;
#pragma unroll
    for (int e = 0; e < 8; e++) out[e * 1024] = vs[e];
}

// ---- scaler second half: ||V1|| over the 3-axis of VpB (bf16 in) ----
__global__ __launch_bounds__(256) void scaler_norm(const short* __restrict__ VpB,
                                                   short* __restrict__ scaler) {
    int idx = blockIdx.x * 256 + threadIdx.x;
    int jj = (idx & 127) * 4;
    int row = idx >> 7;
    float ss0 = 0.f, ss1 = 0.f, ss2 = 0.f, ss3 = 0.f;
#pragma unroll
    for (int c = 0; c < 3; c++) {
        short4 v = *(const short4*)(VpB + ((long)row * 3 + c) * 1024 + jj);
        float x0 = b2f(v.x), x1 = b2f(v.y), x2 = b2f(v.z), x3 = b2f(v.w);
        ss0 += x0 * x0; ss1 += x1 * x1; ss2 += x2 * x2; ss3 += x3 * x3;
    }
    short4 o;
    o.x = f2b(sqrtf(ss0)); o.y = f2b(sqrtf(ss1));
    o.z = f2b(sqrtf(ss2)); o.w = f2b(sqrtf(ss3));
    *(short4*)(scaler + (long)row * 1024 + 512 + jj) = o;
}

extern "C" void kernel_launch(void* const* d_in, const int* in_sizes, int n_in,
                              void* d_out, int out_size, void* d_ws, size_t ws_size,
                              hipStream_t stream) {
    const float* H    = (const float*)d_in[0];
    const float* V    = (const float*)d_in[1];
    const float* Dm   = (const float*)d_in[2];
    const float* rbf  = (const float*)d_in[3];
    const int*   mask = (const int*)d_in[4];
    const float* Wq   = (const float*)d_in[5];
    const float* bq   = (const float*)d_in[6];
    const float* Wk   = (const float*)d_in[7];
    const float* bk   = (const float*)d_in[8];
    const float* Wvs  = (const float*)d_in[9];
    const float* bvs  = (const float*)d_in[10];
    const float* Wvv  = (const float*)d_in[11];
    const float* Wo   = (const float*)d_in[12];
    const float* bo   = (const float*)d_in[13];
    const float* Wvo  = (const float*)d_in[14];
    const float* ln1g = (const float*)d_in[15];
    const float* ln1b = (const float*)d_in[16];
    const float* Wlv  = (const float*)d_in[17];
    const float* W1   = (const float*)d_in[18];
    const float* b1   = (const float*)d_in[19];
    const float* W2   = (const float*)d_in[20];
    const float* b2   = (const float*)d_in[21];
    const float* ln2g = (const float*)d_in[22];
    const float* ln2b = (const float*)d_in[23];

    char* wsb = (char*)d_ws;
    auto KB = [&](long kb) { return (void*)(wsb + kb * 1024l); };
    // weights (persistent through the call)
    short* WqkvT = (short*)KB(0);
    short* WvvT  = (short*)KB(4608);
    short* WoT   = (short*)KB(5120);
    short* WvoT  = (short*)KB(5632);
    short* WlvT  = (short*)KB(6144);
    short* W1T   = (short*)KB(7168);
    short* W2T   = (short*)KB(11264);
    float* bqkv  = (float*)KB(15360);
    // phase 1
    short* Hqkv = (short*)KB(15384);
    short* VvR  = (short*)KB(33816);
    short* VaT  = (short*)KB(39960);
    short* Hn   = (short*)KB(48152);
    short* Vbf  = (short*)KB(50200);
    short* Hres = (short*)KB(56344);   // contiguous with Vres
    short* Vres = (short*)KB(58392);
    float* maskadd = (float*)KB(64536);
    // phase 2 (reuses dead phase-1 regions)
    short* Vbf2   = (short*)KB(15384);
    short* VpB    = (short*)KB(21528);  // bf16 [6144][1024], 12MB
    short* scaler = (short*)KB(46104);
    short* t1     = (short*)KB(50200);

    float* outH = (float*)d_out;
    float* outV = outH + (size_t)Bc * Nseq * Dh;

    // ---- single merged prep launch ----
    PrepJobs a;
    const float* srcs[9] = {Wq, Wk, Wvs, Wvv, Wo, Wvo, Wlv, W1, W2};
    short* dsts[9] = {WqkvT, WqkvT + 2048 * 512, WqkvT + 4096 * 512,
                      WvvT, WoT, WvoT, WlvT, W1T, W2T};
    int Ks[9] = {512, 512, 512, 512, 512, 512, 512, 1024, 2048};
    int Ns[9] = {2048, 2048, 512, 512, 512, 512, 1024, 2048, 1024};
    float scl[9] = {FACT * LOG2E, 1.f, 1.f, 1.f, 1.f, 1.f, 1.f, 1.f, 1.f};
    int base = 0;
    for (int j = 0; j < 9; j++) {
        a.W[j] = srcs[j]; a.Wt[j] = dsts[j];
        a.K[j] = Ks[j]; a.N[j] = Ns[j];
        a.nx[j] = Ns[j] / 32;
        a.scale[j] = scl[j];
        a.base[j] = base;
        base += (Ns[j] / 32) * (Ks[j] / 32);
    }
    a.base_convk = base;
    a.base_bprep = base + 3072;
    a.base_mask  = base + 3072 + 18;
    a.V = V; a.Vbf = Vbf;
    a.bq = bq; a.bk = bk; a.bvs = bvs; a.bqkv = bqkv;
    a.mask = mask; a.maskadd = maskadd;
    int prep_blocks = a.base_mask + 8;
    prep_k<<<prep_blocks, 256, 0, stream>>>(a);

    // LN1 -> bf16
    ln_kernel<short><<<2048, 256, 0, stream>>>(H, ln1g, ln1b, Hn, 512);
    // merged QKV + Vvv projection
    gemm_qkv_vvv<<<dim3(36, 64), 256, 0, stream>>>(Hn, WqkvT, Vbf, WvvT, Hqkv, VvR, bqkv);
    vattn_t8<<<2048, 256, 0, stream>>>(Hqkv + 4096, 4608, VvR, VaT);

    // fused flash attention v9: 512 blocks x 256 threads, KVBLK=64
    flash_attn<<<dim3(512), 256, 0, stream>>>(Hqkv, Hqkv + 2048, VaT, rbf, Dm, maskadd,
                                              Hres, Vres, 4608);

    // merged Wo + Wvo output projections (f32 into d_out; Wvo also emits bf16 Vbf2)
    gemm_out<<<dim3(4, 64), 256, 0, stream>>>(Hres, WoT, WvoT, outH, H, V, Vbf2, bo);
    // LN2 writes bf16 directly into scaler[:, :512]
    ln_kernel<short><<<2048, 256, 0, stream>>>(outH, ln2g, ln2b, scaler, 1024);
    // Vp = V_new @ Wlv (bf16 out)
    gemm_bf16<<<dim3(8, 48, 1), 256, 0, stream>>>(Vbf2, 512, 0, WlvT, 512, 0, VpB, 1024, 0,
                                                  nullptr, nullptr, 0, 0, nullptr, 512, 2);
    scaler_norm<<<1024, 256, 0, stream>>>(VpB, scaler);
    gemm_bf16<<<dim3(16, 16, 1), 256, 0, stream>>>(scaler, 1024, 0, W1T, 1024, 0, t1, 2048, 0,
                                                   b1, nullptr, 0, 0, nullptr, 1024, 3);
    // W2 GEMM with fused final update
    gemm_w2f<<<dim3(8, 16), 256, 0, stream>>>(t1, W2T, b2, outH, outV, VpB);
}

// Round 15
// 274.598 us; speedup vs baseline: 1.0152x; 1.0152x over previous
//
#include <hip/hip_runtime.h>
#include <math.h>

constexpr int Bc = 2, Nseq = 1024, Dh = 512, Nh = 16, Dhead = 32;
constexpr float FACT = 0.08838834764831845f; // 0.5/sqrt(32)
constexpr float LOG2E = 1.4426950408889634f;

typedef __attribute__((ext_vector_type(8))) __bf16 bf16x8;
typedef __attribute__((ext_vector_type(4))) float f32x4;

__device__ __forceinline__ short f2b(float x) {
    union { float f; unsigned u; } v; v.f = x;
    unsigned r = v.u + 0x7fffu + ((v.u >> 16) & 1u);
    return (short)(r >> 16);
}
__device__ __forceinline__ float b2f(short s) {
    union { unsigned u; float f; } v; v.u = ((unsigned)(unsigned short)s) << 16;
    return v.f;
}

#define GL2LDS(g, s) __builtin_amdgcn_global_load_lds(                  \
    (const void __attribute__((address_space(1)))*)(g),                 \
    (void __attribute__((address_space(3)))*)(s), 16, 0, 0)

// ---- shared 128x128-tile bf16 MFMA mainloop (async GL2LDS staging) ----
__device__ __forceinline__ void mfma_loop(const short* __restrict__ A, int lda,
                                          const short* __restrict__ B, int ldb,
                                          int K, short* __restrict__ smA,
                                          short* __restrict__ smB, f32x4 acc[4][4]) {
    const int tid = threadIdx.x;
    const int lane = tid & 63;
    const int w = tid >> 6;
    const int wr = (w >> 1) * 64, wc = (w & 1) * 64;
    const int lr = lane & 15;
    const int srow = tid >> 3;   // 0..31
    const int scol = tid & 7;    // 16B chunk 0..7
    for (int k0 = 0; k0 < K; k0 += 64) {
        __syncthreads();  // prior iteration's LDS reads complete
#pragma unroll
        for (int r = 0; r < 4; r++) {
            int row = r * 32 + srow;
            int gc = scol ^ (row & 7);  // pre-swizzled source
            GL2LDS(A + (long)row * lda + k0 + gc * 8, smA + row * 64 + scol * 8);
            GL2LDS(B + (long)row * ldb + k0 + gc * 8, smB + row * 64 + scol * 8);
        }
        __syncthreads();  // vmcnt(0) drain -> tiles visible
#pragma unroll
        for (int h = 0; h < 2; h++) {
            int cb = h * 4 + (lane >> 4);
            bf16x8 af[4], bv[4];
#pragma unroll
            for (int i = 0; i < 4; i++) {
                int row = wr + i * 16 + lr;
                af[i] = *(const bf16x8*)(smA + row * 64 + ((cb ^ (row & 7)) << 3));
            }
#pragma unroll
            for (int j = 0; j < 4; j++) {
                int row = wc + j * 16 + lr;
                bv[j] = *(const bf16x8*)(smB + row * 64 + ((cb ^ (row & 7)) << 3));
            }
            __builtin_amdgcn_s_setprio(1);
#pragma unroll
            for (int i = 0; i < 4; i++)
#pragma unroll
                for (int j = 0; j < 4; j++)
                    acc[i][j] = __builtin_amdgcn_mfma_f32_16x16x32_bf16(af[i], bv[j], acc[i][j], 0, 0, 0);
            __builtin_amdgcn_s_setprio(0);
        }
    }
}

// flags: 1 = silu, 2 = output bf16; aux != null -> also store bf16 copy to aux
__global__ __launch_bounds__(256) void gemm_bf16(
    const short* __restrict__ A, int lda, long sAz,
    const short* __restrict__ B, int ldb, long sBz,
    void* __restrict__ C, int ldc, long sCz,
    const float* __restrict__ bias,
    const float* __restrict__ resid, int ldr, long sRz,
    short* __restrict__ aux,
    int K, int flags)
{
    __shared__ short smA[128 * 64], smB[128 * 64];
    const long z = blockIdx.z;
    const short* Ab = A + z * sAz + (long)blockIdx.y * 128 * lda;
    const short* Bb = B + z * sBz + (long)blockIdx.x * 128 * ldb;
    f32x4 acc[4][4] = {};
    mfma_loop(Ab, lda, Bb, ldb, K, smA, smB, acc);
    const int tid = threadIdx.x, lane = tid & 63, w = tid >> 6;
    const int wr = (w >> 1) * 64, wc = (w & 1) * 64, lr = lane & 15, r0 = (lane >> 4) * 4;
    const int m0 = blockIdx.y * 128, n0 = blockIdx.x * 128;
    float* Cf = (float*)C; short* Cs = (short*)C;
    const float* rz = resid ? resid + z * sRz : nullptr;
#pragma unroll
    for (int i = 0; i < 4; i++)
#pragma unroll
        for (int j = 0; j < 4; j++) {
            int col = n0 + wc + j * 16 + lr;
            float bv = bias ? bias[col] : 0.f;
#pragma unroll
            for (int q = 0; q < 4; q++) {
                int row = m0 + wr + i * 16 + r0 + q;
                float c = acc[i][j][q] + bv;
                if (rz) c += rz[(long)row * ldr + col];
                if (flags & 1) c = c / (1.f + __expf(-c));
                long off = z * sCz + (long)row * ldc + col;
                if (flags & 2) Cs[off] = f2b(c); else Cf[off] = c;
                if (aux) aux[off] = f2b(c);
            }
        }
}

// ---- merged QKV + Vvv projections in one dispatch ----
__global__ __launch_bounds__(256) void gemm_qkv_vvv(
    const short* __restrict__ Hn, const short* __restrict__ WqkvT,
    const short* __restrict__ Vbf, const short* __restrict__ WvvT,
    short* __restrict__ Hqkv, short* __restrict__ VvR,
    const float* __restrict__ bqkv)
{
    __shared__ short smA[128 * 64], smB[128 * 64];
    const bool qkv = blockIdx.y < 16;
    if (!qkv && blockIdx.x >= 4) return;
    const int yy = qkv ? blockIdx.y : blockIdx.y - 16;
    const short* Ab = (qkv ? Hn : Vbf) + (long)yy * 128 * 512;
    const short* Bb = (qkv ? WqkvT : WvvT) + (long)blockIdx.x * 128 * 512;
    f32x4 acc[4][4] = {};
    mfma_loop(Ab, 512, Bb, 512, 512, smA, smB, acc);
    const int tid = threadIdx.x, lane = tid & 63, w = tid >> 6;
    const int wr = (w >> 1) * 64, wc = (w & 1) * 64, lr = lane & 15, r0 = (lane >> 4) * 4;
    const int m0 = yy * 128, n0 = blockIdx.x * 128;
    short* Cs = qkv ? Hqkv : VvR;
    const int ldc = qkv ? 4608 : 512;
#pragma unroll
    for (int i = 0; i < 4; i++)
#pragma unroll
        for (int j = 0; j < 4; j++) {
            int col = n0 + wc + j * 16 + lr;
            float bv = qkv ? bqkv[col] : 0.f;
#pragma unroll
            for (int q = 0; q < 4; q++) {
                int row = m0 + wr + i * 16 + r0 + q;
                Cs[(long)row * ldc + col] = f2b(acc[i][j][q] + bv);
            }
        }
}

// ---- merged Wo + Wvo output projections (A = [Hres|Vres] contiguous) ----
__global__ __launch_bounds__(256) void gemm_out(
    const short* __restrict__ Ares, const short* __restrict__ WoT,
    const short* __restrict__ WvoT, float* __restrict__ outHV,
    const float* __restrict__ H, const float* __restrict__ V,
    short* __restrict__ Vbf2, const float* __restrict__ bo)
{
    __shared__ short smA[128 * 64], smB[128 * 64];
    const bool isH = blockIdx.y < 16;
    const short* Ab = Ares + (long)blockIdx.y * 128 * 512;
    const short* Bb = (isH ? WoT : WvoT) + (long)blockIdx.x * 128 * 512;
    f32x4 acc[4][4] = {};
    mfma_loop(Ab, 512, Bb, 512, 512, smA, smB, acc);
    const int tid = threadIdx.x, lane = tid & 63, w = tid >> 6;
    const int wr = (w >> 1) * 64, wc = (w & 1) * 64, lr = lane & 15, r0 = (lane >> 4) * 4;
    const int m0 = blockIdx.y * 128, n0 = blockIdx.x * 128;
#pragma unroll
    for (int i = 0; i < 4; i++)
#pragma unroll
        for (int j = 0; j < 4; j++) {
            int col = n0 + wc + j * 16 + lr;
            float bv = isH ? bo[col] : 0.f;
#pragma unroll
            for (int q = 0; q < 4; q++) {
                int row = m0 + wr + i * 16 + r0 + q;
                float c = acc[i][j][q] + bv;
                if (isH) c += H[(long)row * 512 + col];
                else     c += V[(long)(row - 2048) * 512 + col];
                outHV[(long)row * 512 + col] = c;
                if (!isH) Vbf2[(long)(row - 2048) * 512 + col] = f2b(c);
            }
        }
}

// ---- fused flash attention v10: kv-split x2. 256 thr, 4 warps x 16 q-rows,
// QBLK=64, KVBLK=64, 40KB LDS, grid 1024 -> 4 blocks/CU. Each block covers
// half the kv range (8 iters) and emits un-normalized partials (O bf16 +
// m/l f32). Register-staged K/V, warp-private bias/P, 2 barriers/iter,
// log2 softmax + deferred rescale, XCD-aware mapping. ----
__global__ __launch_bounds__(256, 2) void flash_attn(
    const short* __restrict__ Hq, const short* __restrict__ Hk,
    const short* __restrict__ VaT, const float* __restrict__ rbf,
    const float* __restrict__ Dm, const float* __restrict__ maskadd,
    short* __restrict__ Opart, float* __restrict__ mpart,
    float* __restrict__ lpart, int ldq)
{
    __shared__ short smK[64 * 128];    // [kv][d]   16KB
    __shared__ short smV[128 * 64];    // [d][kv]   16KB
    __shared__ short smP[4 * 16 * 64]; // per-warp bias->P, 8KB
    const int xcd = blockIdx.x & 7, idx = blockIdx.x >> 3;  // idx 0..127
    const int s = (idx >> 5) * 8 + xcd;   // slice 0..31, 4 slice-groups per XCD
    const int qt = (idx >> 1) & 15;
    const int p = idx & 1;                // kv split half
    const int b = s >> 4, h = s & 15;
    const int q0 = qt * 64;
    const int kb0 = p * 512;
    const int tid = threadIdx.x, lane = tid & 63, w = tid >> 6;
    const int lr = lane & 15, hi = lane >> 4, r0 = hi * 4;
    const int c16 = tid & 15, rS = tid >> 4;   // K staging
    const int c8 = tid & 7, rS8 = tid >> 3;    // V staging
    short* smPw = smP + w * 1024;

    bf16x8 qf[4];
    {
        const short* qb = Hq + ((long)b * Nseq + q0 + w * 16 + lr) * ldq + h * 128 + hi * 8;
#pragma unroll
        for (int kk = 0; kk < 4; kk++) qf[kk] = *(const bf16x8*)(qb + kk * 32);
    }

    f32x4 oac[8] = {};
    float ml[4], ll[4];
#pragma unroll
    for (int q = 0; q < 4; q++) { ml[q] = -INFINITY; ll[q] = 0.f; }

    const short* Kg = Hk + (long)b * Nseq * ldq + h * 128;
    const short* Vg = VaT + (long)s * 128 * Nseq;
    const float* rbb = rbf + ((long)s * Nseq + q0 + w * 16) * Nseq;
    const float* Dbb = Dm + ((long)b * Nseq + q0 + w * 16) * Nseq;
    const float* mab = maskadd + b * Nseq;
    const int bcol = (lane & 15) * 4, brow = lane >> 4;

    for (int kt = 0; kt < 8; kt++) {
        const int kv0 = kb0 + kt * 64;
        __syncthreads();  // (1) prior iteration's LDS reads complete
        {
            bf16x8 t8[4];
#pragma unroll
            for (int r = 0; r < 4; r++)
                t8[r] = *(const bf16x8*)(Kg + (long)(kv0 + rS + r * 16) * ldq + c16 * 8);
#pragma unroll
            for (int r = 0; r < 4; r++) {
                int row = rS + r * 16;
                *(bf16x8*)(smK + row * 128 + ((c16 ^ (row & 15)) << 3)) = t8[r];
            }
#pragma unroll
            for (int r = 0; r < 4; r++)
                t8[r] = *(const bf16x8*)(Vg + (long)(rS8 + r * 32) * Nseq + kv0 + c8 * 8);
#pragma unroll
            for (int r = 0; r < 4; r++) {
                int row = rS8 + r * 32;
                *(bf16x8*)(smV + row * 64 + ((c8 ^ (row & 7)) << 3)) = t8[r];
            }
        }
        {
            short4 hb[4];
            float4 mk = *(const float4*)(mab + kv0 + bcol);
#pragma unroll
            for (int it = 0; it < 4; it++) {
                int row = it * 4 + brow;
                float4 rv = *(const float4*)(rbb + (long)row * Nseq + kv0 + bcol);
                float4 dv = *(const float4*)(Dbb + (long)row * Nseq + kv0 + bcol);
                hb[it].x = f2b((rv.x + dv.x + mk.x) * LOG2E);
                hb[it].y = f2b((rv.y + dv.y + mk.y) * LOG2E);
                hb[it].z = f2b((rv.z + dv.z + mk.z) * LOG2E);
                hb[it].w = f2b((rv.w + dv.w + mk.w) * LOG2E);
            }
            int ch = bcol >> 3;
#pragma unroll
            for (int it = 0; it < 4; it++) {
                int row = it * 4 + brow;
                *(short4*)(smPw + row * 64 + ((ch ^ (row & 7)) << 3) + (bcol & 7)) = hb[it];
            }
        }
        __syncthreads();  // (2) K/V/bias staged

        // S = Q @ K^T (log2 domain), 64 kv cols
        f32x4 sac[4] = {};
#pragma unroll
        for (int kk = 0; kk < 4; kk++) {
            int cb = kk * 4 + hi;
            bf16x8 kv8[4];
#pragma unroll
            for (int j = 0; j < 4; j++) {
                int row = j * 16 + lr;
                kv8[j] = *(const bf16x8*)(smK + row * 128 + ((cb ^ (row & 15)) << 3));
            }
#pragma unroll
            for (int j = 0; j < 4; j++)
                sac[j] = __builtin_amdgcn_mfma_f32_16x16x32_bf16(qf[kk], kv8[j], sac[j], 0, 0, 0);
        }
        // bias add (warp-private LDS) + row max
        float tmax[4];
#pragma unroll
        for (int q = 0; q < 4; q++) tmax[q] = -INFINITY;
#pragma unroll
        for (int j = 0; j < 4; j++) {
            int col = j * 16 + lr;
            int ch = col >> 3, in8 = col & 7;
#pragma unroll
            for (int q = 0; q < 4; q++) {
                int row = r0 + q;
                float x = sac[j][q] + b2f(smPw[row * 64 + ((ch ^ (row & 7)) << 3) + in8]);
                sac[j][q] = x;
                tmax[q] = fmaxf(tmax[q], x);
            }
        }
#pragma unroll
        for (int st = 1; st < 16; st <<= 1)
#pragma unroll
            for (int q = 0; q < 4; q++) tmax[q] = fmaxf(tmax[q], __shfl_xor(tmax[q], st));
        // deferred rescale (T13)
        float dm = -INFINITY;
#pragma unroll
        for (int q = 0; q < 4; q++) dm = fmaxf(dm, tmax[q] - ml[q]);
        if (!__all(dm <= 8.f)) {
#pragma unroll
            for (int q = 0; q < 4; q++) {
                float mn = fmaxf(ml[q], tmax[q]);
                float sc = exp2f(ml[q] - mn);
                ml[q] = mn;
                ll[q] *= sc;
#pragma unroll
                for (int j = 0; j < 8; j++) oac[j][q] *= sc;
            }
        }
        float rsum[4] = {0.f, 0.f, 0.f, 0.f};
#pragma unroll
        for (int j = 0; j < 4; j++)
#pragma unroll
            for (int q = 0; q < 4; q++) {
                float pp = exp2f(sac[j][q] - ml[q]);
                sac[j][q] = pp;
                rsum[q] += pp;
            }
#pragma unroll
        for (int st = 1; st < 16; st <<= 1)
#pragma unroll
            for (int q = 0; q < 4; q++) rsum[q] += __shfl_xor(rsum[q], st);
#pragma unroll
        for (int q = 0; q < 4; q++) ll[q] += rsum[q];
        // P -> warp-private LDS (same-warp ordering; no barrier)
#pragma unroll
        for (int j = 0; j < 4; j++) {
            int col = j * 16 + lr;
            int ch = col >> 3, in8 = col & 7;
#pragma unroll
            for (int q = 0; q < 4; q++) {
                int row = r0 + q;
                smPw[row * 64 + ((ch ^ (row & 7)) << 3) + in8] = f2b(sac[j][q]);
            }
        }
        // O += P @ V (kv = 64 -> 2 kk steps)
#pragma unroll
        for (int kk = 0; kk < 2; kk++) {
            int cb = kk * 4 + hi;
            bf16x8 paf = *(const bf16x8*)(smPw + lr * 64 + ((cb ^ (lr & 7)) << 3));
            bf16x8 vv[8];
#pragma unroll
            for (int j = 0; j < 8; j++) {
                int row = j * 16 + lr;
                vv[j] = *(const bf16x8*)(smV + row * 64 + ((cb ^ (row & 7)) << 3));
            }
#pragma unroll
            for (int j = 0; j < 8; j++)
                oac[j] = __builtin_amdgcn_mfma_f32_16x16x32_bf16(paf, vv[j], oac[j], 0, 0, 0);
        }
    }
    // ---- store un-normalized partials ----
    const int g = s * 16 + qt;
    short* Op = Opart + ((long)(p * 512 + g) * 64) * 128;
#pragma unroll
    for (int j = 0; j < 8; j++) {
        int d = j * 16 + lr;
#pragma unroll
        for (int q = 0; q < 4; q++) {
            int row = w * 16 + r0 + q;
            Op[(long)row * 128 + d] = f2b(oac[j][q]);
        }
    }
    if (lr == 0) {
#pragma unroll
        for (int q = 0; q < 4; q++) {
            long off = (long)(p * 512 + g) * 64 + w * 16 + r0 + q;
            mpart[off] = ml[q];
            lpart[off] = ll[q];
        }
    }
}

// ---- merge kv-split partials -> Hres/Vres ----
__global__ __launch_bounds__(256) void merge_k(
    const short* __restrict__ Opart, const float* __restrict__ mpart,
    const float* __restrict__ lpart, short* __restrict__ Hres,
    short* __restrict__ Vres)
{
    int idx = blockIdx.x * 256 + threadIdx.x;  // 512*64*32 = 1048576
    int dc = idx & 31, row = (idx >> 5) & 63, g = idx >> 11;
    int d = dc * 4;
    long off = (long)g * 64 + row;
    float m0 = mpart[off], m1 = mpart[512l * 64 + off];
    float l0 = lpart[off], l1 = lpart[512l * 64 + off];
    float mm = fmaxf(m0, m1);
    float w0 = exp2f(m0 - mm), w1 = exp2f(m1 - mm);
    float inv = 1.f / (l0 * w0 + l1 * w1);
    short4 a4 = *(const short4*)(Opart + ((long)g * 64 + row) * 128 + d);
    short4 b4 = *(const short4*)(Opart + ((long)(512 + g) * 64 + row) * 128 + d);
    short4 o;
    o.x = f2b((b2f(a4.x) * w0 + b2f(b4.x) * w1) * inv);
    o.y = f2b((b2f(a4.y) * w0 + b2f(b4.y) * w1) * inv);
    o.z = f2b((b2f(a4.z) * w0 + b2f(b4.z) * w1) * inv);
    o.w = f2b((b2f(a4.w) * w0 + b2f(b4.w) * w1) * inv);
    int s = g >> 4, qt = g & 15;
    int b = s >> 4, h = s & 15;
    int n = qt * 64 + row;
    if (d < 32) {
        *(short4*)(Hres + ((long)b * Nseq + n) * 512 + h * 32 + d) = o;
    } else {
        int c3 = (d - 32) >> 5, dd = (d - 32) & 31;
        *(short4*)(Vres + (((long)b * Nseq + n) * 3 + c3) * 512 + h * 32 + dd) = o;
    }
}

// ---- merged prep kernel: 9 weight transposes + V convert + bqkv + maskadd ----
struct PrepJobs {
    const float* W[9];
    short* Wt[9];
    int K[9], N[9], nx[9], base[9];
    float scale[9];
    int base_convk, base_bprep, base_mask;
    const float* V; short* Vbf;
    const float* bq; const float* bk; const float* bvs; float* bqkv;
    const int* mask; float* maskadd;
};

__global__ __launch_bounds__(256) void prep_k(PrepJobs a) {
    int bid = blockIdx.x;
    int tid = threadIdx.x;
    if (bid >= a.base_convk) {
        if (bid < a.base_bprep) {
            int i = (bid - a.base_convk) * 256 + tid;
            float4 v = ((const float4*)a.V)[i];
            short4 s;
            s.x = f2b(v.x); s.y = f2b(v.y); s.z = f2b(v.z); s.w = f2b(v.w);
            ((short4*)a.Vbf)[i] = s;
        } else if (bid < a.base_mask) {
            int i = (bid - a.base_bprep) * 256 + tid;
            float v;
            if (i < 2048) v = a.bq[i] * (FACT * LOG2E);
            else if (i < 4096) v = a.bk[i - 2048];
            else v = a.bvs[i - 4096];
            a.bqkv[i] = v;
        } else {
            int i = (bid - a.base_mask) * 256 + tid;
            a.maskadd[i] = a.mask[i] ? 0.f : -1e30f;
        }
        return;
    }
    int j = 0;
#pragma unroll
    for (int t = 1; t < 9; t++) j = (bid >= a.base[t]) ? t : j;
    const float* W = a.W[j];
    short* Wt = a.Wt[j];
    int K = a.K[j], N = a.N[j];
    float scale = a.scale[j];
    int local = bid - a.base[j];
    int nx = a.nx[j];
    int bx = local % nx, by = local / nx;
    __shared__ float t[32][33];
    int n0 = bx * 32, k0 = by * 32;
    int tx = tid & 31, ty = tid >> 5;
#pragma unroll
    for (int r = 0; r < 4; r++) t[ty + r * 8][tx] = W[(long)(k0 + ty + r * 8) * N + n0 + tx];
    __syncthreads();
#pragma unroll
    for (int r = 0; r < 4; r++) Wt[(long)(n0 + ty + r * 8) * K + k0 + tx] = f2b(t[tx][ty + r * 8] * scale);
}

__device__ __forceinline__ void stv(float* p, float v) { *p = v; }
__device__ __forceinline__ void stv(short* p, float v) { *p = f2b(v); }

// LayerNorm, output row stride ldo
template <typename OT>
__global__ __launch_bounds__(256) void ln_kernel(const float* __restrict__ x,
                                                 const float* __restrict__ g,
                                                 const float* __restrict__ b,
                                                 OT* __restrict__ y, int ldo) {
    int row = blockIdx.x;
    const float* xr = x + (long)row * Dh;
    OT* yr = y + (long)row * ldo;
    int tid = threadIdx.x;
    float v0 = xr[tid], v1 = xr[tid + 256];
    __shared__ float red[256];
    red[tid] = v0 + v1;
    __syncthreads();
    for (int o = 128; o > 0; o >>= 1) { if (tid < o) red[tid] += red[tid + o]; __syncthreads(); }
    float mean = red[0] * (1.0f / Dh);
    __syncthreads();
    float d0 = v0 - mean, d1 = v1 - mean;
    red[tid] = d0 * d0 + d1 * d1;
    __syncthreads();
    for (int o = 128; o > 0; o >>= 1) { if (tid < o) red[tid] += red[tid + o]; __syncthreads(); }
    float rstd = rsqrtf(red[0] * (1.0f / Dh) + 1e-5f);
    stv(&yr[tid], d0 * rstd * g[tid] + b[tid]);
    stv(&yr[tid + 256], d1 * rstd * g[tid + 256] + b[tid + 256]);
}

// ---- Vattn_t gather, vectorized ----
__global__ __launch_bounds__(256) void vattn_t8(const short* __restrict__ Hv, int ldh,
                                                const short* __restrict__ Vv,
                                                short* __restrict__ VaT) {
    int idx = blockIdx.x * 256 + threadIdx.x;
    int m = idx & 1023;
    int c = (idx >> 10) & 15;
    int s = idx >> 14;
    int b = s >> 4, h = s & 15;
    bf16x8 v;
    if (c < 4) {
        v = *(const bf16x8*)(Hv + ((long)b * Nseq + m) * ldh + h * 32 + c * 8);
    } else {
        int c3 = (c - 4) >> 2, dd = ((c - 4) & 3) * 8;
        v = *(const bf16x8*)(Vv + (((long)b * Nseq + m) * 3 + c3) * 512 + h * 32 + dd);
    }
    short* out = VaT + (long)s * 128 * 1024 + (long)c * 8 * 1024 + m;
    const short* vs = (const short*)&v;
#pragma unroll
    for (int e = 0; e < 8; e++) out[e * 1024] = vs[e];
}

// ---- scaler second half: ||V1|| over the 3-axis of Vp (float4) ----
__global__ __launch_bounds__(256) void scaler_norm(const float* __restrict__ Vp,
                                                   short* __restrict__ scaler) {
    int idx = blockIdx.x * 256 + threadIdx.x;
    int jj = (idx & 127) * 4;
    int row = idx >> 7;
    float4 ss = {0.f, 0.f, 0.f, 0.f};
#pragma unroll
    for (int c = 0; c < 3; c++) {
        float4 v = *(const float4*)(Vp + ((long)row * 3 + c) * 1024 + jj);
        ss.x += v.x * v.x; ss.y += v.y * v.y; ss.z += v.z * v.z; ss.w += v.w * v.w;
    }
    short4 o;
    o.x = f2b(sqrtf(ss.x)); o.y = f2b(sqrtf(ss.y));
    o.z = f2b(sqrtf(ss.z)); o.w = f2b(sqrtf(ss.w));
    *(short4*)(scaler + (long)row * 1024 + 512 + jj) = o;
}

// ---- final: H += s[:512]; V += s[512:] * V2 (float4) ----
__global__ __launch_bounds__(256) void final_k(float* __restrict__ outH,
                                               float* __restrict__ outV,
                                               const float* __restrict__ s,
                                               const float* __restrict__ Vp) {
    int idx = blockIdx.x * 256 + threadIdx.x;
    int jj = (idx & 127) * 4;
    int row = idx >> 7;
    float4 s1 = *(const float4*)(s + (long)row * 1024 + jj);
    float4 h = *(const float4*)(outH + (long)row * 512 + jj);
    h.x += s1.x; h.y += s1.y; h.z += s1.z; h.w += s1.w;
    *(float4*)(outH + (long)row * 512 + jj) = h;
    float4 vu = *(const float4*)(s + (long)row * 1024 + 512 + jj);
#pragma unroll
    for (int c = 0; c < 3; c++) {
        float4 v2 = *(const float4*)(Vp + ((long)row * 3 + c) * 1024 + 512 + jj);
        float* vp = outV + ((long)row * 3 + c) * 512 + jj;
        float4 vo = *(const float4*)vp;
        vo.x += vu.x * v2.x; vo.y += vu.y * v2.y;
        vo.z += vu.z * v2.z; vo.w += vu.w * v2.w;
        *(float4*)vp = vo;
    }
}

extern "C" void kernel_launch(void* const* d_in, const int* in_sizes, int n_in,
                              void* d_out, int out_size, void* d_ws, size_t ws_size,
                              hipStream_t stream) {
    const float* H    = (const float*)d_in[0];
    const float* V    = (const float*)d_in[1];
    const float* Dm   = (const float*)d_in[2];
    const float* rbf  = (const float*)d_in[3];
    const int*   mask = (const int*)d_in[4];
    const float* Wq   = (const float*)d_in[5];
    const float* bq   = (const float*)d_in[6];
    const float* Wk   = (const float*)d_in[7];
    const float* bk   = (const float*)d_in[8];
    const float* Wvs  = (const float*)d_in[9];
    const float* bvs  = (const float*)d_in[10];
    const float* Wvv  = (const float*)d_in[11];
    const float* Wo   = (const float*)d_in[12];
    const float* bo   = (const float*)d_in[13];
    const float* Wvo  = (const float*)d_in[14];
    const float* ln1g = (const float*)d_in[15];
    const float* ln1b = (const float*)d_in[16];
    const float* Wlv  = (const float*)d_in[17];
    const float* W1   = (const float*)d_in[18];
    const float* b1   = (const float*)d_in[19];
    const float* W2   = (const float*)d_in[20];
    const float* b2   = (const float*)d_in[21];
    const float* ln2g = (const float*)d_in[22];
    const float* ln2b = (const float*)d_in[23];

    char* wsb = (char*)d_ws;
    auto KB = [&](long kb) { return (void*)(wsb + kb * 1024l); };
    // weights (persistent through the call)
    short* WqkvT = (short*)KB(0);
    short* WvvT  = (short*)KB(4608);
    short* WoT   = (short*)KB(5120);
    short* WvoT  = (short*)KB(5632);
    short* WlvT  = (short*)KB(6144);
    short* W1T   = (short*)KB(7168);
    short* W2T   = (short*)KB(11264);
    float* bqkv  = (float*)KB(15360);
    // phase 1
    short* Hqkv = (short*)KB(15384);
    short* VvR  = (short*)KB(33816);
    short* VaT  = (short*)KB(39960);
    short* Hn   = (short*)KB(48152);
    short* Vbf  = (short*)KB(50200);
    short* Hres = (short*)KB(56344);   // contiguous with Vres
    short* Vres = (short*)KB(58392);
    float* maskadd = (float*)KB(64536);
    // kv-split partials (dead after merge_k)
    short* Opart = (short*)KB(67000);  // [2][512][64][128] bf16, 16.8MB
    float* mpart = (float*)KB(83500);  // [2][512][64] f32, 256KB
    float* lpart = (float*)KB(83800);  // 256KB -> ends ~84060
    // phase 2 (reuses dead phase-1 regions)
    short* Vbf2   = (short*)KB(15384);
    float* Vp     = (float*)KB(21528);
    short* scaler = (short*)KB(46104);
    short* t1     = (short*)KB(50200);
    float* sbuf   = (float*)KB(58392);

    float* outH = (float*)d_out;
    float* outV = outH + (size_t)Bc * Nseq * Dh;

    // ---- single merged prep launch ----
    PrepJobs a;
    const float* srcs[9] = {Wq, Wk, Wvs, Wvv, Wo, Wvo, Wlv, W1, W2};
    short* dsts[9] = {WqkvT, WqkvT + 2048 * 512, WqkvT + 4096 * 512,
                      WvvT, WoT, WvoT, WlvT, W1T, W2T};
    int Ks[9] = {512, 512, 512, 512, 512, 512, 512, 1024, 2048};
    int Ns[9] = {2048, 2048, 512, 512, 512, 512, 1024, 2048, 1024};
    float scl[9] = {FACT * LOG2E, 1.f, 1.f, 1.f, 1.f, 1.f, 1.f, 1.f, 1.f};
    int base = 0;
    for (int j = 0; j < 9; j++) {
        a.W[j] = srcs[j]; a.Wt[j] = dsts[j];
        a.K[j] = Ks[j]; a.N[j] = Ns[j];
        a.nx[j] = Ns[j] / 32;
        a.scale[j] = scl[j];
        a.base[j] = base;
        base += (Ns[j] / 32) * (Ks[j] / 32);
    }
    a.base_convk = base;
    a.base_bprep = base + 3072;
    a.base_mask  = base + 3072 + 18;
    a.V = V; a.Vbf = Vbf;
    a.bq = bq; a.bk = bk; a.bvs = bvs; a.bqkv = bqkv;
    a.mask = mask; a.maskadd = maskadd;
    int prep_blocks = a.base_mask + 8;
    prep_k<<<prep_blocks, 256, 0, stream>>>(a);

    // LN1 -> bf16
    ln_kernel<short><<<2048, 256, 0, stream>>>(H, ln1g, ln1b, Hn, 512);
    // merged QKV + Vvv projection
    gemm_qkv_vvv<<<dim3(36, 64), 256, 0, stream>>>(Hn, WqkvT, Vbf, WvvT, Hqkv, VvR, bqkv);
    vattn_t8<<<2048, 256, 0, stream>>>(Hqkv + 4096, 4608, VvR, VaT);

    // fused flash attention v10: 1024 blocks (kv-split x2), 4 blocks/CU
    flash_attn<<<dim3(1024), 256, 0, stream>>>(Hqkv, Hqkv + 2048, VaT, rbf, Dm, maskadd,
                                               Opart, mpart, lpart, 4608);
    merge_k<<<4096, 256, 0, stream>>>(Opart, mpart, lpart, Hres, Vres);

    // merged Wo + Wvo output projections (f32 into d_out; Wvo also emits bf16 Vbf2)
    gemm_out<<<dim3(4, 64), 256, 0, stream>>>(Hres, WoT, WvoT, outH, H, V, Vbf2, bo);
    // LN2 writes bf16 directly into scaler[:, :512]
    ln_kernel<short><<<2048, 256, 0, stream>>>(outH, ln2g, ln2b, scaler, 1024);
    gemm_bf16<<<dim3(8, 48, 1), 256, 0, stream>>>(Vbf2, 512, 0, WlvT, 512, 0, Vp, 1024, 0,
                                                  nullptr, nullptr, 0, 0, nullptr, 512, 0);
    scaler_norm<<<1024, 256, 0, stream>>>(Vp, scaler);
    gemm_bf16<<<dim3(16, 16, 1), 256, 0, stream>>>(scaler, 1024, 0, W1T, 1024, 0, t1, 2048, 0,
                                                   b1, nullptr, 0, 0, nullptr, 1024, 3);
    gemm_bf16<<<dim3(8, 16, 1), 256, 0, stream>>>(t1, 2048, 0, W2T, 2048, 0, sbuf, 1024, 0,
                                                  b2, nullptr, 0, 0, nullptr, 2048, 0);
    final_k<<<1024, 256, 0, stream>>>(outH, outV, sbuf, Vp);
}

// Round 16
// 249.277 us; speedup vs baseline: 1.1183x; 1.1016x over previous
//
#include <hip/hip_runtime.h>
#include <math.h>

constexpr int Bc = 2, Nseq = 1024, Dh = 512, Nh = 16, Dhead = 32;
constexpr float FACT = 0.08838834764831845f; // 0.5/sqrt(32)
constexpr float LOG2E = 1.4426950408889634f;

typedef __attribute__((ext_vector_type(8))) __bf16 bf16x8;
typedef __attribute__((ext_vector_type(4))) float f32x4;

__device__ __forceinline__ short f2b(float x) {
    union { float f; unsigned u; } v; v.f = x;
    unsigned r = v.u + 0x7fffu + ((v.u >> 16) & 1u);
    return (short)(r >> 16);
}
__device__ __forceinline__ float b2f(short s) {
    union { unsigned u; float f; } v; v.u = ((unsigned)(unsigned short)s) << 16;
    return v.f;
}

#define GL2LDS(g, s) __builtin_amdgcn_global_load_lds(                  \
    (const void __attribute__((address_space(1)))*)(g),                 \
    (void __attribute__((address_space(3)))*)(s), 16, 0, 0)

// ---- shared 128x128-tile bf16 MFMA mainloop (async GL2LDS staging) ----
__device__ __forceinline__ void mfma_loop(const short* __restrict__ A, int lda,
                                          const short* __restrict__ B, int ldb,
                                          int K, short* __restrict__ smA,
                                          short* __restrict__ smB, f32x4 acc[4][4]) {
    const int tid = threadIdx.x;
    const int lane = tid & 63;
    const int w = tid >> 6;
    const int wr = (w >> 1) * 64, wc = (w & 1) * 64;
    const int lr = lane & 15;
    const int srow = tid >> 3;   // 0..31
    const int scol = tid & 7;    // 16B chunk 0..7
    for (int k0 = 0; k0 < K; k0 += 64) {
        __syncthreads();  // prior iteration's LDS reads complete
#pragma unroll
        for (int r = 0; r < 4; r++) {
            int row = r * 32 + srow;
            int gc = scol ^ (row & 7);  // pre-swizzled source
            GL2LDS(A + (long)row * lda + k0 + gc * 8, smA + row * 64 + scol * 8);
            GL2LDS(B + (long)row * ldb + k0 + gc * 8, smB + row * 64 + scol * 8);
        }
        __syncthreads();  // vmcnt(0) drain -> tiles visible
#pragma unroll
        for (int h = 0; h < 2; h++) {
            int cb = h * 4 + (lane >> 4);
            bf16x8 af[4], bv[4];
#pragma unroll
            for (int i = 0; i < 4; i++) {
                int row = wr + i * 16 + lr;
                af[i] = *(const bf16x8*)(smA + row * 64 + ((cb ^ (row & 7)) << 3));
            }
#pragma unroll
            for (int j = 0; j < 4; j++) {
                int row = wc + j * 16 + lr;
                bv[j] = *(const bf16x8*)(smB + row * 64 + ((cb ^ (row & 7)) << 3));
            }
            __builtin_amdgcn_s_setprio(1);
#pragma unroll
            for (int i = 0; i < 4; i++)
#pragma unroll
                for (int j = 0; j < 4; j++)
                    acc[i][j] = __builtin_amdgcn_mfma_f32_16x16x32_bf16(af[i], bv[j], acc[i][j], 0, 0, 0);
            __builtin_amdgcn_s_setprio(0);
        }
    }
}

// flags: 1 = silu, 2 = output bf16; aux != null -> also store bf16 copy to aux
__global__ __launch_bounds__(256) void gemm_bf16(
    const short* __restrict__ A, int lda, long sAz,
    const short* __restrict__ B, int ldb, long sBz,
    void* __restrict__ C, int ldc, long sCz,
    const float* __restrict__ bias,
    const float* __restrict__ resid, int ldr, long sRz,
    short* __restrict__ aux,
    int K, int flags)
{
    __shared__ short smA[128 * 64], smB[128 * 64];
    const long z = blockIdx.z;
    const short* Ab = A + z * sAz + (long)blockIdx.y * 128 * lda;
    const short* Bb = B + z * sBz + (long)blockIdx.x * 128 * ldb;
    f32x4 acc[4][4] = {};
    mfma_loop(Ab, lda, Bb, ldb, K, smA, smB, acc);
    const int tid = threadIdx.x, lane = tid & 63, w = tid >> 6;
    const int wr = (w >> 1) * 64, wc = (w & 1) * 64, lr = lane & 15, r0 = (lane >> 4) * 4;
    const int m0 = blockIdx.y * 128, n0 = blockIdx.x * 128;
    float* Cf = (float*)C; short* Cs = (short*)C;
    const float* rz = resid ? resid + z * sRz : nullptr;
#pragma unroll
    for (int i = 0; i < 4; i++)
#pragma unroll
        for (int j = 0; j < 4; j++) {
            int col = n0 + wc + j * 16 + lr;
            float bv = bias ? bias[col] : 0.f;
#pragma unroll
            for (int q = 0; q < 4; q++) {
                int row = m0 + wr + i * 16 + r0 + q;
                float c = acc[i][j][q] + bv;
                if (rz) c += rz[(long)row * ldr + col];
                if (flags & 1) c = c / (1.f + __expf(-c));
                long off = z * sCz + (long)row * ldc + col;
                if (flags & 2) Cs[off] = f2b(c); else Cf[off] = c;
                if (aux) aux[off] = f2b(c);
            }
        }
}

// ---- merged QKV + Vvv projections, flat 1-D grid (768 blocks, no idles) ----
// blocks 0..575: QKV (x=bid%36, y=bid/36); blocks 576..767: Vvv (x=l%4, y=l/4)
__global__ __launch_bounds__(256) void gemm_qkv_vvv(
    const short* __restrict__ Hn, const short* __restrict__ WqkvT,
    const short* __restrict__ Vbf, const short* __restrict__ WvvT,
    short* __restrict__ Hqkv, short* __restrict__ VvR,
    const float* __restrict__ bqkv)
{
    __shared__ short smA[128 * 64], smB[128 * 64];
    const int bid = blockIdx.x;
    const bool qkv = bid < 576;
    const int bx = qkv ? (bid % 36) : ((bid - 576) & 3);
    const int by = qkv ? (bid / 36) : ((bid - 576) >> 2);
    const short* Ab = (qkv ? Hn : Vbf) + (long)by * 128 * 512;
    const short* Bb = (qkv ? WqkvT : WvvT) + (long)bx * 128 * 512;
    f32x4 acc[4][4] = {};
    mfma_loop(Ab, 512, Bb, 512, 512, smA, smB, acc);
    const int tid = threadIdx.x, lane = tid & 63, w = tid >> 6;
    const int wr = (w >> 1) * 64, wc = (w & 1) * 64, lr = lane & 15, r0 = (lane >> 4) * 4;
    const int m0 = by * 128, n0 = bx * 128;
    short* Cs = qkv ? Hqkv : VvR;
    const int ldc = qkv ? 4608 : 512;
#pragma unroll
    for (int i = 0; i < 4; i++)
#pragma unroll
        for (int j = 0; j < 4; j++) {
            int col = n0 + wc + j * 16 + lr;
            float bv = qkv ? bqkv[col] : 0.f;
#pragma unroll
            for (int q = 0; q < 4; q++) {
                int row = m0 + wr + i * 16 + r0 + q;
                Cs[(long)row * ldc + col] = f2b(acc[i][j][q] + bv);
            }
        }
}

// ---- merged Wo + Wvo output projections (A = [Hres|Vres] contiguous) ----
__global__ __launch_bounds__(256) void gemm_out(
    const short* __restrict__ Ares, const short* __restrict__ WoT,
    const short* __restrict__ WvoT, float* __restrict__ outHV,
    const float* __restrict__ H, const float* __restrict__ V,
    short* __restrict__ Vbf2, const float* __restrict__ bo)
{
    __shared__ short smA[128 * 64], smB[128 * 64];
    const bool isH = blockIdx.y < 16;
    const short* Ab = Ares + (long)blockIdx.y * 128 * 512;
    const short* Bb = (isH ? WoT : WvoT) + (long)blockIdx.x * 128 * 512;
    f32x4 acc[4][4] = {};
    mfma_loop(Ab, 512, Bb, 512, 512, smA, smB, acc);
    const int tid = threadIdx.x, lane = tid & 63, w = tid >> 6;
    const int wr = (w >> 1) * 64, wc = (w & 1) * 64, lr = lane & 15, r0 = (lane >> 4) * 4;
    const int m0 = blockIdx.y * 128, n0 = blockIdx.x * 128;
#pragma unroll
    for (int i = 0; i < 4; i++)
#pragma unroll
        for (int j = 0; j < 4; j++) {
            int col = n0 + wc + j * 16 + lr;
            float bv = isH ? bo[col] : 0.f;
#pragma unroll
            for (int q = 0; q < 4; q++) {
                int row = m0 + wr + i * 16 + r0 + q;
                float c = acc[i][j][q] + bv;
                if (isH) c += H[(long)row * 512 + col];
                else     c += V[(long)(row - 2048) * 512 + col];
                outHV[(long)row * 512 + col] = c;
                if (!isH) Vbf2[(long)(row - 2048) * 512 + col] = f2b(c);
            }
        }
}

// ---- fused flash attention v5 (best measured ~83us): 256 thr, 4 warps x 16
// q-rows, QBLK=64, 80KB LDS -> 2 blocks/CU, register-staged K/V, warp-private
// bias/P, 2 barriers/iter, log2 softmax + deferred rescale, XCD mapping. ----
__global__ __launch_bounds__(256, 2) void flash_attn(
    const short* __restrict__ Hq, const short* __restrict__ Hk,
    const short* __restrict__ VaT, const float* __restrict__ rbf,
    const float* __restrict__ Dm, const float* __restrict__ maskadd,
    short* __restrict__ Hres, short* __restrict__ Vres, int ldq)
{
    __shared__ short smK[128 * 128];    // [kv m][d]   32KB
    __shared__ short smV[128 * 128];    // [d][kv m]   32KB
    __shared__ short smP[4 * 16 * 128]; // per-warp bias->P, 16KB
    const int xcd = blockIdx.x & 7, idx = blockIdx.x >> 3;
    const int s = (idx >> 4) * 8 + xcd;
    const int qt = idx & 15;
    const int b = s >> 4, h = s & 15;
    const int q0 = qt * 64;
    const int tid = threadIdx.x, lane = tid & 63, w = tid >> 6;
    const int lr = lane & 15, hi = lane >> 4, r0 = hi * 4;
    const int c16 = tid & 15, rS = tid >> 4;
    short* smPw = smP + w * 2048;

    bf16x8 qf[4];
    {
        const short* qb = Hq + ((long)b * Nseq + q0 + w * 16 + lr) * ldq + h * 128 + hi * 8;
#pragma unroll
        for (int kk = 0; kk < 4; kk++) qf[kk] = *(const bf16x8*)(qb + kk * 32);
    }

    f32x4 oac[8] = {};
    float ml[4], ll[4];
#pragma unroll
    for (int q = 0; q < 4; q++) { ml[q] = -INFINITY; ll[q] = 0.f; }

    const short* Kg = Hk + (long)b * Nseq * ldq + h * 128;
    const short* Vg = VaT + (long)s * 128 * Nseq;
    const float* rbb = rbf + ((long)s * Nseq + q0 + w * 16) * Nseq;
    const float* Dbb = Dm + ((long)b * Nseq + q0 + w * 16) * Nseq;
    const float* mab = maskadd + b * Nseq;
    const int bcol = (lane & 31) * 4, brow2 = lane >> 5;

    for (int kt = 0; kt < 8; kt++) {
        __syncthreads();  // (1) prior iteration's LDS reads complete
        {
            bf16x8 t8[8];
#pragma unroll
            for (int r = 0; r < 8; r++)
                t8[r] = *(const bf16x8*)(Kg + (long)(kt * 128 + rS + r * 16) * ldq + c16 * 8);
#pragma unroll
            for (int r = 0; r < 8; r++) {
                int row = rS + r * 16;
                *(bf16x8*)(smK + row * 128 + (c16 ^ (row & 15)) * 8) = t8[r];
            }
#pragma unroll
            for (int r = 0; r < 8; r++)
                t8[r] = *(const bf16x8*)(Vg + (long)(rS + r * 16) * Nseq + kt * 128 + c16 * 8);
#pragma unroll
            for (int r = 0; r < 8; r++) {
                int row = rS + r * 16;
                *(bf16x8*)(smV + row * 128 + (c16 ^ (row & 15)) * 8) = t8[r];
            }
        }
        {
            short4 hb[8];
            float4 mk = *(const float4*)(mab + kt * 128 + bcol);
#pragma unroll
            for (int it = 0; it < 8; it++) {
                int row = it * 2 + brow2;
                float4 rv = *(const float4*)(rbb + (long)row * Nseq + kt * 128 + bcol);
                float4 dv = *(const float4*)(Dbb + (long)row * Nseq + kt * 128 + bcol);
                hb[it].x = f2b((rv.x + dv.x + mk.x) * LOG2E);
                hb[it].y = f2b((rv.y + dv.y + mk.y) * LOG2E);
                hb[it].z = f2b((rv.z + dv.z + mk.z) * LOG2E);
                hb[it].w = f2b((rv.w + dv.w + mk.w) * LOG2E);
            }
            int ch = bcol >> 3;
#pragma unroll
            for (int it = 0; it < 8; it++) {
                int row = it * 2 + brow2;
                *(short4*)(smPw + row * 128 + ((ch ^ (row & 7)) << 3) + (bcol & 7)) = hb[it];
            }
        }
        __syncthreads();  // (2) K/V/bias staged

        // S = Q @ K^T (log2 domain)
        f32x4 sac[8] = {};
#pragma unroll
        for (int kk = 0; kk < 4; kk++) {
            int cb = kk * 4 + hi;
            bf16x8 kv8[8];
#pragma unroll
            for (int j = 0; j < 8; j++) {
                int row = j * 16 + lr;
                kv8[j] = *(const bf16x8*)(smK + row * 128 + ((cb ^ (row & 15)) << 3));
            }
#pragma unroll
            for (int j = 0; j < 8; j++)
                sac[j] = __builtin_amdgcn_mfma_f32_16x16x32_bf16(qf[kk], kv8[j], sac[j], 0, 0, 0);
        }
        // bias add (warp-private LDS) + row max
        float tmax[4];
#pragma unroll
        for (int q = 0; q < 4; q++) tmax[q] = -INFINITY;
#pragma unroll
        for (int j = 0; j < 8; j++) {
            int col = j * 16 + lr;
            int ch = col >> 3, in8 = col & 7;
#pragma unroll
            for (int q = 0; q < 4; q++) {
                int row = r0 + q;
                float x = sac[j][q] + b2f(smPw[row * 128 + ((ch ^ (row & 7)) << 3) + in8]);
                sac[j][q] = x;
                tmax[q] = fmaxf(tmax[q], x);
            }
        }
#pragma unroll
        for (int st = 1; st < 16; st <<= 1)
#pragma unroll
            for (int q = 0; q < 4; q++) tmax[q] = fmaxf(tmax[q], __shfl_xor(tmax[q], st));
        // deferred rescale (T13)
        float dm = -INFINITY;
#pragma unroll
        for (int q = 0; q < 4; q++) dm = fmaxf(dm, tmax[q] - ml[q]);
        if (!__all(dm <= 8.f)) {
#pragma unroll
            for (int q = 0; q < 4; q++) {
                float mn = fmaxf(ml[q], tmax[q]);
                float sc = exp2f(ml[q] - mn);
                ml[q] = mn;
                ll[q] *= sc;
#pragma unroll
                for (int j = 0; j < 8; j++) oac[j][q] *= sc;
            }
        }
        float rsum[4] = {0.f, 0.f, 0.f, 0.f};
#pragma unroll
        for (int j = 0; j < 8; j++)
#pragma unroll
            for (int q = 0; q < 4; q++) {
                float p = exp2f(sac[j][q] - ml[q]);
                sac[j][q] = p;
                rsum[q] += p;
            }
#pragma unroll
        for (int st = 1; st < 16; st <<= 1)
#pragma unroll
            for (int q = 0; q < 4; q++) rsum[q] += __shfl_xor(rsum[q], st);
#pragma unroll
        for (int q = 0; q < 4; q++) ll[q] += rsum[q];
        // P -> warp-private LDS (same-warp ordering via lgkmcnt; no barrier)
#pragma unroll
        for (int j = 0; j < 8; j++) {
            int col = j * 16 + lr;
            int ch = col >> 3, in8 = col & 7;
#pragma unroll
            for (int q = 0; q < 4; q++) {
                int row = r0 + q;
                smPw[row * 128 + ((ch ^ (row & 7)) << 3) + in8] = f2b(sac[j][q]);
            }
        }
        // O += P @ V
#pragma unroll
        for (int kk = 0; kk < 4; kk++) {
            int cb = kk * 4 + hi;
            bf16x8 paf = *(const bf16x8*)(smPw + lr * 128 + ((cb ^ (lr & 7)) << 3));
            bf16x8 vv[8];
#pragma unroll
            for (int j = 0; j < 8; j++) {
                int row = j * 16 + lr;
                vv[j] = *(const bf16x8*)(smV + row * 128 + ((cb ^ (row & 15)) << 3));
            }
#pragma unroll
            for (int j = 0; j < 8; j++)
                oac[j] = __builtin_amdgcn_mfma_f32_16x16x32_bf16(paf, vv[j], oac[j], 0, 0, 0);
        }
    }
    // normalize + scatter
    float inv[4];
#pragma unroll
    for (int q = 0; q < 4; q++) inv[q] = 1.f / ll[q];
#pragma unroll
    for (int j = 0; j < 8; j++) {
        int d = j * 16 + lr;
#pragma unroll
        for (int q = 0; q < 4; q++) {
            int n = q0 + w * 16 + r0 + q;
            float o = oac[j][q] * inv[q];
            if (d < 32) Hres[((long)b * Nseq + n) * 512 + h * 32 + d] = f2b(o);
            else {
                int c3 = (d - 32) >> 5, dd = (d - 32) & 31;
                Vres[(((long)b * Nseq + n) * 3 + c3) * 512 + h * 32 + dd] = f2b(o);
            }
        }
    }
}

// ---- merged prep kernel: 9 weight transposes + V convert + bqkv + maskadd ----
struct PrepJobs {
    const float* W[9];
    short* Wt[9];
    int K[9], N[9], nx[9], base[9];
    float scale[9];
    int base_convk, base_bprep, base_mask;
    const float* V; short* Vbf;
    const float* bq; const float* bk; const float* bvs; float* bqkv;
    const int* mask; float* maskadd;
};

__global__ __launch_bounds__(256) void prep_k(PrepJobs a) {
    int bid = blockIdx.x;
    int tid = threadIdx.x;
    if (bid >= a.base_convk) {
        if (bid < a.base_bprep) {
            int i = (bid - a.base_convk) * 256 + tid;
            float4 v = ((const float4*)a.V)[i];
            short4 s;
            s.x = f2b(v.x); s.y = f2b(v.y); s.z = f2b(v.z); s.w = f2b(v.w);
            ((short4*)a.Vbf)[i] = s;
        } else if (bid < a.base_mask) {
            int i = (bid - a.base_bprep) * 256 + tid;
            float v;
            if (i < 2048) v = a.bq[i] * (FACT * LOG2E);
            else if (i < 4096) v = a.bk[i - 2048];
            else v = a.bvs[i - 4096];
            a.bqkv[i] = v;
        } else {
            int i = (bid - a.base_mask) * 256 + tid;
            a.maskadd[i] = a.mask[i] ? 0.f : -1e30f;
        }
        return;
    }
    int j = 0;
#pragma unroll
    for (int t = 1; t < 9; t++) j = (bid >= a.base[t]) ? t : j;
    const float* W = a.W[j];
    short* Wt = a.Wt[j];
    int K = a.K[j], N = a.N[j];
    float scale = a.scale[j];
    int local = bid - a.base[j];
    int nx = a.nx[j];
    int bx = local % nx, by = local / nx;
    __shared__ float t[32][33];
    int n0 = bx * 32, k0 = by * 32;
    int tx = tid & 31, ty = tid >> 5;
#pragma unroll
    for (int r = 0; r < 4; r++) t[ty + r * 8][tx] = W[(long)(k0 + ty + r * 8) * N + n0 + tx];
    __syncthreads();
#pragma unroll
    for (int r = 0; r < 4; r++) Wt[(long)(n0 + ty + r * 8) * K + k0 + tx] = f2b(t[tx][ty + r * 8] * scale);
}

__device__ __forceinline__ void stv(float* p, float v) { *p = v; }
__device__ __forceinline__ void stv(short* p, float v) { *p = f2b(v); }

// LayerNorm, output row stride ldo
template <typename OT>
__global__ __launch_bounds__(256) void ln_kernel(const float* __restrict__ x,
                                                 const float* __restrict__ g,
                                                 const float* __restrict__ b,
                                                 OT* __restrict__ y, int ldo) {
    int row = blockIdx.x;
    const float* xr = x + (long)row * Dh;
    OT* yr = y + (long)row * ldo;
    int tid = threadIdx.x;
    float v0 = xr[tid], v1 = xr[tid + 256];
    __shared__ float red[256];
    red[tid] = v0 + v1;
    __syncthreads();
    for (int o = 128; o > 0; o >>= 1) { if (tid < o) red[tid] += red[tid + o]; __syncthreads(); }
    float mean = red[0] * (1.0f / Dh);
    __syncthreads();
    float d0 = v0 - mean, d1 = v1 - mean;
    red[tid] = d0 * d0 + d1 * d1;
    __syncthreads();
    for (int o = 128; o > 0; o >>= 1) { if (tid < o) red[tid] += red[tid + o]; __syncthreads(); }
    float rstd = rsqrtf(red[0] * (1.0f / Dh) + 1e-5f);
    stv(&yr[tid], d0 * rstd * g[tid] + b[tid]);
    stv(&yr[tid + 256], d1 * rstd * g[tid + 256] + b[tid + 256]);
}

// ---- Vattn_t gather, vectorized ----
__global__ __launch_bounds__(256) void vattn_t8(const short* __restrict__ Hv, int ldh,
                                                const short* __restrict__ Vv,
                                                short* __restrict__ VaT) {
    int idx = blockIdx.x * 256 + threadIdx.x;
    int m = idx & 1023;
    int c = (idx >> 10) & 15;
    int s = idx >> 14;
    int b = s >> 4, h = s & 15;
    bf16x8 v;
    if (c < 4) {
        v = *(const bf16x8*)(Hv + ((long)b * Nseq + m) * ldh + h * 32 + c * 8);
    } else {
        int c3 = (c - 4) >> 2, dd = ((c - 4) & 3) * 8;
        v = *(const bf16x8*)(Vv + (((long)b * Nseq + m) * 3 + c3) * 512 + h * 32 + dd);
    }
    short* out = VaT + (long)s * 128 * 1024 + (long)c * 8 * 1024 + m;
    const short* vs = (const short*)&v;
#pragma unroll
    for (int e = 0; e < 8; e++) out[e * 1024] = vs[e];
}

// ---- scaler second half: ||V1|| over the 3-axis of Vp (float4) ----
__global__ __launch_bounds__(256) void scaler_norm(const float* __restrict__ Vp,
                                                   short* __restrict__ scaler) {
    int idx = blockIdx.x * 256 + threadIdx.x;
    int jj = (idx & 127) * 4;
    int row = idx >> 7;
    float4 ss = {0.f, 0.f, 0.f, 0.f};
#pragma unroll
    for (int c = 0; c < 3; c++) {
        float4 v = *(const float4*)(Vp + ((long)row * 3 + c) * 1024 + jj);
        ss.x += v.x * v.x; ss.y += v.y * v.y; ss.z += v.z * v.z; ss.w += v.w * v.w;
    }
    short4 o;
    o.x = f2b(sqrtf(ss.x)); o.y = f2b(sqrtf(ss.y));
    o.z = f2b(sqrtf(ss.z)); o.w = f2b(sqrtf(ss.w));
    *(short4*)(scaler + (long)row * 1024 + 512 + jj) = o;
}

// ---- final: H += s[:512]; V += s[512:] * V2 (float4) ----
__global__ __launch_bounds__(256) void final_k(float* __restrict__ outH,
                                               float* __restrict__ outV,
                                               const float* __restrict__ s,
                                               const float* __restrict__ Vp) {
    int idx = blockIdx.x * 256 + threadIdx.x;
    int jj = (idx & 127) * 4;
    int row = idx >> 7;
    float4 s1 = *(const float4*)(s + (long)row * 1024 + jj);
    float4 h = *(const float4*)(outH + (long)row * 512 + jj);
    h.x += s1.x; h.y += s1.y; h.z += s1.z; h.w += s1.w;
    *(float4*)(outH + (long)row * 512 + jj) = h;
    float4 vu = *(const float4*)(s + (long)row * 1024 + 512 + jj);
#pragma unroll
    for (int c = 0; c < 3; c++) {
        float4 v2 = *(const float4*)(Vp + ((long)row * 3 + c) * 1024 + 512 + jj);
        float* vp = outV + ((long)row * 3 + c) * 512 + jj;
        float4 vo = *(const float4*)vp;
        vo.x += vu.x * v2.x; vo.y += vu.y * v2.y;
        vo.z += vu.z * v2.z; vo.w += vu.w * v2.w;
        *(float4*)vp = vo;
    }
}

extern "C" void kernel_launch(void* const* d_in, const int* in_sizes, int n_in,
                              void* d_out, int out_size, void* d_ws, size_t ws_size,
                              hipStream_t stream) {
    const float* H    = (const float*)d_in[0];
    const float* V    = (const float*)d_in[1];
    const float* Dm   = (const float*)d_in[2];
    const float* rbf  = (const float*)d_in[3];
    const int*   mask = (const int*)d_in[4];
    const float* Wq   = (const float*)d_in[5];
    const float* bq   = (const float*)d_in[6];
    const float* Wk   = (const float*)d_in[7];
    const float* bk   = (const float*)d_in[8];
    const float* Wvs  = (const float*)d_in[9];
    const float* bvs  = (const float*)d_in[10];
    const float* Wvv  = (const float*)d_in[11];
    const float* Wo   = (const float*)d_in[12];
    const float* bo   = (const float*)d_in[13];
    const float* Wvo  = (const float*)d_in[14];
    const float* ln1g = (const float*)d_in[15];
    const float* ln1b = (const float*)d_in[16];
    const float* Wlv  = (const float*)d_in[17];
    const float* W1   = (const float*)d_in[18];
    const float* b1   = (const float*)d_in[19];
    const float* W2   = (const float*)d_in[20];
    const float* b2   = (const float*)d_in[21];
    const float* ln2g = (const float*)d_in[22];
    const float* ln2b = (const float*)d_in[23];

    char* wsb = (char*)d_ws;
    auto KB = [&](long kb) { return (void*)(wsb + kb * 1024l); };
    // weights (persistent through the call)
    short* WqkvT = (short*)KB(0);
    short* WvvT  = (short*)KB(4608);
    short* WoT   = (short*)KB(5120);
    short* WvoT  = (short*)KB(5632);
    short* WlvT  = (short*)KB(6144);
    short* W1T   = (short*)KB(7168);
    short* W2T   = (short*)KB(11264);
    float* bqkv  = (float*)KB(15360);
    // phase 1
    short* Hqkv = (short*)KB(15384);
    short* VvR  = (short*)KB(33816);
    short* VaT  = (short*)KB(39960);
    short* Hn   = (short*)KB(48152);
    short* Vbf  = (short*)KB(50200);
    short* Hres = (short*)KB(56344);   // contiguous with Vres
    short* Vres = (short*)KB(58392);
    float* maskadd = (float*)KB(64536);
    // phase 2 (reuses dead phase-1 regions)
    short* Vbf2   = (short*)KB(15384);
    float* Vp     = (float*)KB(21528);
    short* scaler = (short*)KB(46104);
    short* t1     = (short*)KB(50200);
    float* sbuf   = (float*)KB(58392);

    float* outH = (float*)d_out;
    float* outV = outH + (size_t)Bc * Nseq * Dh;

    // ---- single merged prep launch ----
    PrepJobs a;
    const float* srcs[9] = {Wq, Wk, Wvs, Wvv, Wo, Wvo, Wlv, W1, W2};
    short* dsts[9] = {WqkvT, WqkvT + 2048 * 512, WqkvT + 4096 * 512,
                      WvvT, WoT, WvoT, WlvT, W1T, W2T};
    int Ks[9] = {512, 512, 512, 512, 512, 512, 512, 1024, 2048};
    int Ns[9] = {2048, 2048, 512, 512, 512, 512, 1024, 2048, 1024};
    float scl[9] = {FACT * LOG2E, 1.f, 1.f, 1.f, 1.f, 1.f, 1.f, 1.f, 1.f};
    int base = 0;
    for (int j = 0; j < 9; j++) {
        a.W[j] = srcs[j]; a.Wt[j] = dsts[j];
        a.K[j] = Ks[j]; a.N[j] = Ns[j];
        a.nx[j] = Ns[j] / 32;
        a.scale[j] = scl[j];
        a.base[j] = base;
        base += (Ns[j] / 32) * (Ks[j] / 32);
    }
    a.base_convk = base;
    a.base_bprep = base + 3072;
    a.base_mask  = base + 3072 + 18;
    a.V = V; a.Vbf = Vbf;
    a.bq = bq; a.bk = bk; a.bvs = bvs; a.bqkv = bqkv;
    a.mask = mask; a.maskadd = maskadd;
    int prep_blocks = a.base_mask + 8;
    prep_k<<<prep_blocks, 256, 0, stream>>>(a);

    // LN1 -> bf16
    ln_kernel<short><<<2048, 256, 0, stream>>>(H, ln1g, ln1b, Hn, 512);
    // merged QKV + Vvv projection (flat 768-block grid)
    gemm_qkv_vvv<<<768, 256, 0, stream>>>(Hn, WqkvT, Vbf, WvvT, Hqkv, VvR, bqkv);
    vattn_t8<<<2048, 256, 0, stream>>>(Hqkv + 4096, 4608, VvR, VaT);

    // fused flash attention: 512 blocks x 256 threads (v5 structure)
    flash_attn<<<dim3(512), 256, 0, stream>>>(Hqkv, Hqkv + 2048, VaT, rbf, Dm, maskadd,
                                              Hres, Vres, 4608);

    // merged Wo + Wvo output projections (f32 into d_out; Wvo also emits bf16 Vbf2)
    gemm_out<<<dim3(4, 64), 256, 0, stream>>>(Hres, WoT, WvoT, outH, H, V, Vbf2, bo);
    // LN2 writes bf16 directly into scaler[:, :512]
    ln_kernel<short><<<2048, 256, 0, stream>>>(outH, ln2g, ln2b, scaler, 1024);
    gemm_bf16<<<dim3(8, 48, 1), 256, 0, stream>>>(Vbf2, 512, 0, WlvT, 512, 0, Vp, 1024, 0,
                                                  nullptr, nullptr, 0, 0, nullptr, 512, 0);
    scaler_norm<<<1024, 256, 0, stream>>>(Vp, scaler);
    gemm_bf16<<<dim3(16, 16, 1), 256, 0, stream>>>(scaler, 1024, 0, W1T, 1024, 0, t1, 2048, 0,
                                                   b1, nullptr, 0, 0, nullptr, 1024, 3);
    gemm_bf16<<<dim3(8, 16, 1), 256, 0, stream>>>(t1, 2048, 0, W2T, 2048, 0, sbuf, 1024, 0,
                                                  b2, nullptr, 0, 0, nullptr, 2048, 0);
    final_k<<<1024, 256, 0, stream>>>(outH, outV, sbuf, Vp);
}

// Round 18
// 248.666 us; speedup vs baseline: 1.1211x; 1.0025x over previous
//
#include <hip/hip_runtime.h>
#include <math.h>

constexpr int Bc = 2, Nseq = 1024, Dh = 512, Nh = 16, Dhead = 32;
constexpr float FACT = 0.08838834764831845f; // 0.5/sqrt(32)
constexpr float LOG2E = 1.4426950408889634f;

typedef __attribute__((ext_vector_type(8))) __bf16 bf16x8;
typedef __attribute__((ext_vector_type(4))) float f32x4;

__device__ __forceinline__ short f2b(float x) {
    union { float f; unsigned u; } v; v.f = x;
    unsigned r = v.u + 0x7fffu + ((v.u >> 16) & 1u);
    return (short)(r >> 16);
}
__device__ __forceinline__ float b2f(short s) {
    union { unsigned u; float f; } v; v.u = ((unsigned)(unsigned short)s) << 16;
    return v.f;
}

#define GL2LDS(g, s) __builtin_amdgcn_global_load_lds(                  \
    (const void __attribute__((address_space(1)))*)(g),                 \
    (void __attribute__((address_space(3)))*)(s), 16, 0, 0)

// ---- shared 128x128-tile bf16 MFMA mainloop (async GL2LDS staging) ----
__device__ __forceinline__ void mfma_loop(const short* __restrict__ A, int lda,
                                          const short* __restrict__ B, int ldb,
                                          int K, short* __restrict__ smA,
                                          short* __restrict__ smB, f32x4 acc[4][4]) {
    const int tid = threadIdx.x;
    const int lane = tid & 63;
    const int w = tid >> 6;
    const int wr = (w >> 1) * 64, wc = (w & 1) * 64;
    const int lr = lane & 15;
    const int srow = tid >> 3;   // 0..31
    const int scol = tid & 7;    // 16B chunk 0..7
    for (int k0 = 0; k0 < K; k0 += 64) {
        __syncthreads();  // prior iteration's LDS reads complete
#pragma unroll
        for (int r = 0; r < 4; r++) {
            int row = r * 32 + srow;
            int gc = scol ^ (row & 7);  // pre-swizzled source
            GL2LDS(A + (long)row * lda + k0 + gc * 8, smA + row * 64 + scol * 8);
            GL2LDS(B + (long)row * ldb + k0 + gc * 8, smB + row * 64 + scol * 8);
        }
        __syncthreads();  // vmcnt(0) drain -> tiles visible
#pragma unroll
        for (int h = 0; h < 2; h++) {
            int cb = h * 4 + (lane >> 4);
            bf16x8 af[4], bv[4];
#pragma unroll
            for (int i = 0; i < 4; i++) {
                int row = wr + i * 16 + lr;
                af[i] = *(const bf16x8*)(smA + row * 64 + ((cb ^ (row & 7)) << 3));
            }
#pragma unroll
            for (int j = 0; j < 4; j++) {
                int row = wc + j * 16 + lr;
                bv[j] = *(const bf16x8*)(smB + row * 64 + ((cb ^ (row & 7)) << 3));
            }
            __builtin_amdgcn_s_setprio(1);
#pragma unroll
            for (int i = 0; i < 4; i++)
#pragma unroll
                for (int j = 0; j < 4; j++)
                    acc[i][j] = __builtin_amdgcn_mfma_f32_16x16x32_bf16(af[i], bv[j], acc[i][j], 0, 0, 0);
            __builtin_amdgcn_s_setprio(0);
        }
    }
}

// flags: 1 = silu, 2 = output bf16; aux != null -> also store bf16 copy to aux
__global__ __launch_bounds__(256) void gemm_bf16(
    const short* __restrict__ A, int lda, long sAz,
    const short* __restrict__ B, int ldb, long sBz,
    void* __restrict__ C, int ldc, long sCz,
    const float* __restrict__ bias,
    const float* __restrict__ resid, int ldr, long sRz,
    short* __restrict__ aux,
    int K, int flags)
{
    __shared__ short smA[128 * 64], smB[128 * 64];
    const long z = blockIdx.z;
    const short* Ab = A + z * sAz + (long)blockIdx.y * 128 * lda;
    const short* Bb = B + z * sBz + (long)blockIdx.x * 128 * ldb;
    f32x4 acc[4][4] = {};
    mfma_loop(Ab, lda, Bb, ldb, K, smA, smB, acc);
    const int tid = threadIdx.x, lane = tid & 63, w = tid >> 6;
    const int wr = (w >> 1) * 64, wc = (w & 1) * 64, lr = lane & 15, r0 = (lane >> 4) * 4;
    const int m0 = blockIdx.y * 128, n0 = blockIdx.x * 128;
    float* Cf = (float*)C; short* Cs = (short*)C;
    const float* rz = resid ? resid + z * sRz : nullptr;
#pragma unroll
    for (int i = 0; i < 4; i++)
#pragma unroll
        for (int j = 0; j < 4; j++) {
            int col = n0 + wc + j * 16 + lr;
            float bv = bias ? bias[col] : 0.f;
#pragma unroll
            for (int q = 0; q < 4; q++) {
                int row = m0 + wr + i * 16 + r0 + q;
                float c = acc[i][j][q] + bv;
                if (rz) c += rz[(long)row * ldr + col];
                if (flags & 1) c = c / (1.f + __expf(-c));
                long off = z * sCz + (long)row * ldc + col;
                if (flags & 2) Cs[off] = f2b(c); else Cf[off] = c;
                if (aux) aux[off] = f2b(c);
            }
        }
}

// ---- merged QKV + Vvv projections, flat 1-D grid (768 blocks, no idles) ----
// blocks 0..575: QKV (x=bid%36, y=bid/36); blocks 576..767: Vvv (x=l%4, y=l/4)
__global__ __launch_bounds__(256) void gemm_qkv_vvv(
    const short* __restrict__ Hn, const short* __restrict__ WqkvT,
    const short* __restrict__ Vbf, const short* __restrict__ WvvT,
    short* __restrict__ Hqkv, short* __restrict__ VvR,
    const float* __restrict__ bqkv)
{
    __shared__ short smA[128 * 64], smB[128 * 64];
    const int bid = blockIdx.x;
    const bool qkv = bid < 576;
    const int bx = qkv ? (bid % 36) : ((bid - 576) & 3);
    const int by = qkv ? (bid / 36) : ((bid - 576) >> 2);
    const short* Ab = (qkv ? Hn : Vbf) + (long)by * 128 * 512;
    const short* Bb = (qkv ? WqkvT : WvvT) + (long)bx * 128 * 512;
    f32x4 acc[4][4] = {};
    mfma_loop(Ab, 512, Bb, 512, 512, smA, smB, acc);
    const int tid = threadIdx.x, lane = tid & 63, w = tid >> 6;
    const int wr = (w >> 1) * 64, wc = (w & 1) * 64, lr = lane & 15, r0 = (lane >> 4) * 4;
    const int m0 = by * 128, n0 = bx * 128;
    short* Cs = qkv ? Hqkv : VvR;
    const int ldc = qkv ? 4608 : 512;
#pragma unroll
    for (int i = 0; i < 4; i++)
#pragma unroll
        for (int j = 0; j < 4; j++) {
            int col = n0 + wc + j * 16 + lr;
            float bv = qkv ? bqkv[col] : 0.f;
#pragma unroll
            for (int q = 0; q < 4; q++) {
                int row = m0 + wr + i * 16 + r0 + q;
                Cs[(long)row * ldc + col] = f2b(acc[i][j][q] + bv);
            }
        }
}

// ---- merged Wo + Wvo output projections (A = [Hres|Vres] contiguous) ----
__global__ __launch_bounds__(256) void gemm_out(
    const short* __restrict__ Ares, const short* __restrict__ WoT,
    const short* __restrict__ WvoT, float* __restrict__ outHV,
    const float* __restrict__ H, const float* __restrict__ V,
    short* __restrict__ Vbf2, const float* __restrict__ bo)
{
    __shared__ short smA[128 * 64], smB[128 * 64];
    const bool isH = blockIdx.y < 16;
    const short* Ab = Ares + (long)blockIdx.y * 128 * 512;
    const short* Bb = (isH ? WoT : WvoT) + (long)blockIdx.x * 128 * 512;
    f32x4 acc[4][4] = {};
    mfma_loop(Ab, 512, Bb, 512, 512, smA, smB, acc);
    const int tid = threadIdx.x, lane = tid & 63, w = tid >> 6;
    const int wr = (w >> 1) * 64, wc = (w & 1) * 64, lr = lane & 15, r0 = (lane >> 4) * 4;
    const int m0 = blockIdx.y * 128, n0 = blockIdx.x * 128;
#pragma unroll
    for (int i = 0; i < 4; i++)
#pragma unroll
        for (int j = 0; j < 4; j++) {
            int col = n0 + wc + j * 16 + lr;
            float bv = isH ? bo[col] : 0.f;
#pragma unroll
            for (int q = 0; q < 4; q++) {
                int row = m0 + wr + i * 16 + r0 + q;
                float c = acc[i][j][q] + bv;
                if (isH) c += H[(long)row * 512 + col];
                else     c += V[(long)(row - 2048) * 512 + col];
                outHV[(long)row * 512 + col] = c;
                if (!isH) Vbf2[(long)(row - 2048) * 512 + col] = f2b(c);
            }
        }
}

// ---- fused flash attention v5 (best measured ~83us): 256 thr, 4 warps x 16
// q-rows, QBLK=64, 80KB LDS -> 2 blocks/CU, register-staged K/V, warp-private
// bias/P, 2 barriers/iter, log2 softmax + deferred rescale, XCD mapping. ----
__global__ __launch_bounds__(256, 2) void flash_attn(
    const short* __restrict__ Hq, const short* __restrict__ Hk,
    const short* __restrict__ VaT, const float* __restrict__ rbf,
    const float* __restrict__ Dm, const float* __restrict__ maskadd,
    short* __restrict__ Hres, short* __restrict__ Vres, int ldq)
{
    __shared__ short smK[128 * 128];    // [kv m][d]   32KB
    __shared__ short smV[128 * 128];    // [d][kv m]   32KB
    __shared__ short smP[4 * 16 * 128]; // per-warp bias->P, 16KB
    const int xcd = blockIdx.x & 7, idx = blockIdx.x >> 3;
    const int s = (idx >> 4) * 8 + xcd;
    const int qt = idx & 15;
    const int b = s >> 4, h = s & 15;
    const int q0 = qt * 64;
    const int tid = threadIdx.x, lane = tid & 63, w = tid >> 6;
    const int lr = lane & 15, hi = lane >> 4, r0 = hi * 4;
    const int c16 = tid & 15, rS = tid >> 4;
    short* smPw = smP + w * 2048;

    bf16x8 qf[4];
    {
        const short* qb = Hq + ((long)b * Nseq + q0 + w * 16 + lr) * ldq + h * 128 + hi * 8;
#pragma unroll
        for (int kk = 0; kk < 4; kk++) qf[kk] = *(const bf16x8*)(qb + kk * 32);
    }

    f32x4 oac[8] = {};
    float ml[4], ll[4];
#pragma unroll
    for (int q = 0; q < 4; q++) { ml[q] = -INFINITY; ll[q] = 0.f; }

    const short* Kg = Hk + (long)b * Nseq * ldq + h * 128;
    const short* Vg = VaT + (long)s * 128 * Nseq;
    const float* rbb = rbf + ((long)s * Nseq + q0 + w * 16) * Nseq;
    const float* Dbb = Dm + ((long)b * Nseq + q0 + w * 16) * Nseq;
    const float* mab = maskadd + b * Nseq;
    const int bcol = (lane & 31) * 4, brow2 = lane >> 5;

    for (int kt = 0; kt < 8; kt++) {
        __syncthreads();  // (1) prior iteration's LDS reads complete
        {
            bf16x8 t8[8];
#pragma unroll
            for (int r = 0; r < 8; r++)
                t8[r] = *(const bf16x8*)(Kg + (long)(kt * 128 + rS + r * 16) * ldq + c16 * 8);
#pragma unroll
            for (int r = 0; r < 8; r++) {
                int row = rS + r * 16;
                *(bf16x8*)(smK + row * 128 + (c16 ^ (row & 15)) * 8) = t8[r];
            }
#pragma unroll
            for (int r = 0; r < 8; r++)
                t8[r] = *(const bf16x8*)(Vg + (long)(rS + r * 16) * Nseq + kt * 128 + c16 * 8);
#pragma unroll
            for (int r = 0; r < 8; r++) {
                int row = rS + r * 16;
                *(bf16x8*)(smV + row * 128 + (c16 ^ (row & 15)) * 8) = t8[r];
            }
        }
        {
            short4 hb[8];
            float4 mk = *(const float4*)(mab + kt * 128 + bcol);
#pragma unroll
            for (int it = 0; it < 8; it++) {
                int row = it * 2 + brow2;
                float4 rv = *(const float4*)(rbb + (long)row * Nseq + kt * 128 + bcol);
                float4 dv = *(const float4*)(Dbb + (long)row * Nseq + kt * 128 + bcol);
                hb[it].x = f2b((rv.x + dv.x + mk.x) * LOG2E);
                hb[it].y = f2b((rv.y + dv.y + mk.y) * LOG2E);
                hb[it].z = f2b((rv.z + dv.z + mk.z) * LOG2E);
                hb[it].w = f2b((rv.w + dv.w + mk.w) * LOG2E);
            }
            int ch = bcol >> 3;
#pragma unroll
            for (int it = 0; it < 8; it++) {
                int row = it * 2 + brow2;
                *(short4*)(smPw + row * 128 + ((ch ^ (row & 7)) << 3) + (bcol & 7)) = hb[it];
            }
        }
        __syncthreads();  // (2) K/V/bias staged

        // S = Q @ K^T (log2 domain)
        f32x4 sac[8] = {};
#pragma unroll
        for (int kk = 0; kk < 4; kk++) {
            int cb = kk * 4 + hi;
            bf16x8 kv8[8];
#pragma unroll
            for (int j = 0; j < 8; j++) {
                int row = j * 16 + lr;
                kv8[j] = *(const bf16x8*)(smK + row * 128 + ((cb ^ (row & 15)) << 3));
            }
#pragma unroll
            for (int j = 0; j < 8; j++)
                sac[j] = __builtin_amdgcn_mfma_f32_16x16x32_bf16(qf[kk], kv8[j], sac[j], 0, 0, 0);
        }
        // bias add (warp-private LDS) + row max
        float tmax[4];
#pragma unroll
        for (int q = 0; q < 4; q++) tmax[q] = -INFINITY;
#pragma unroll
        for (int j = 0; j < 8; j++) {
            int col = j * 16 + lr;
            int ch = col >> 3, in8 = col & 7;
#pragma unroll
            for (int q = 0; q < 4; q++) {
                int row = r0 + q;
                float x = sac[j][q] + b2f(smPw[row * 128 + ((ch ^ (row & 7)) << 3) + in8]);
                sac[j][q] = x;
                tmax[q] = fmaxf(tmax[q], x);
            }
        }
#pragma unroll
        for (int st = 1; st < 16; st <<= 1)
#pragma unroll
            for (int q = 0; q < 4; q++) tmax[q] = fmaxf(tmax[q], __shfl_xor(tmax[q], st));
        // deferred rescale (T13)
        float dm = -INFINITY;
#pragma unroll
        for (int q = 0; q < 4; q++) dm = fmaxf(dm, tmax[q] - ml[q]);
        if (!__all(dm <= 8.f)) {
#pragma unroll
            for (int q = 0; q < 4; q++) {
                float mn = fmaxf(ml[q], tmax[q]);
                float sc = exp2f(ml[q] - mn);
                ml[q] = mn;
                ll[q] *= sc;
#pragma unroll
                for (int j = 0; j < 8; j++) oac[j][q] *= sc;
            }
        }
        float rsum[4] = {0.f, 0.f, 0.f, 0.f};
#pragma unroll
        for (int j = 0; j < 8; j++)
#pragma unroll
            for (int q = 0; q < 4; q++) {
                float p = exp2f(sac[j][q] - ml[q]);
                sac[j][q] = p;
                rsum[q] += p;
            }
#pragma unroll
        for (int st = 1; st < 16; st <<= 1)
#pragma unroll
            for (int q = 0; q < 4; q++) rsum[q] += __shfl_xor(rsum[q], st);
#pragma unroll
        for (int q = 0; q < 4; q++) ll[q] += rsum[q];
        // P -> warp-private LDS (same-warp ordering via lgkmcnt; no barrier)
#pragma unroll
        for (int j = 0; j < 8; j++) {
            int col = j * 16 + lr;
            int ch = col >> 3, in8 = col & 7;
#pragma unroll
            for (int q = 0; q < 4; q++) {
                int row = r0 + q;
                smPw[row * 128 + ((ch ^ (row & 7)) << 3) + in8] = f2b(sac[j][q]);
            }
        }
        // O += P @ V
#pragma unroll
        for (int kk = 0; kk < 4; kk++) {
            int cb = kk * 4 + hi;
            bf16x8 paf = *(const bf16x8*)(smPw + lr * 128 + ((cb ^ (lr & 7)) << 3));
            bf16x8 vv[8];
#pragma unroll
            for (int j = 0; j < 8; j++) {
                int row = j * 16 + lr;
                vv[j] = *(const bf16x8*)(smV + row * 128 + ((cb ^ (row & 15)) << 3));
            }
#pragma unroll
            for (int j = 0; j < 8; j++)
                oac[j] = __builtin_amdgcn_mfma_f32_16x16x32_bf16(paf, vv[j], oac[j], 0, 0, 0);
        }
    }
    // normalize + scatter
    float inv[4];
#pragma unroll
    for (int q = 0; q < 4; q++) inv[q] = 1.f / ll[q];
#pragma unroll
    for (int j = 0; j < 8; j++) {
        int d = j * 16 + lr;
#pragma unroll
        for (int q = 0; q < 4; q++) {
            int n = q0 + w * 16 + r0 + q;
            float o = oac[j][q] * inv[q];
            if (d < 32) Hres[((long)b * Nseq + n) * 512 + h * 32 + d] = f2b(o);
            else {
                int c3 = (d - 32) >> 5, dd = (d - 32) & 31;
                Vres[(((long)b * Nseq + n) * 3 + c3) * 512 + h * 32 + dd] = f2b(o);
            }
        }
    }
}

// ---- merged prep kernel: 9 weight transposes + V convert + bqkv + maskadd ----
struct PrepJobs {
    const float* W[9];
    short* Wt[9];
    int K[9], N[9], nx[9], base[9];
    float scale[9];
    int base_convk, base_bprep, base_mask;
    const float* V; short* Vbf;
    const float* bq; const float* bk; const float* bvs; float* bqkv;
    const int* mask; float* maskadd;
};

__global__ __launch_bounds__(256) void prep_k(PrepJobs a) {
    int bid = blockIdx.x;
    int tid = threadIdx.x;
    if (bid >= a.base_convk) {
        if (bid < a.base_bprep) {
            int i = (bid - a.base_convk) * 256 + tid;
            float4 v = ((const float4*)a.V)[i];
            short4 s;
            s.x = f2b(v.x); s.y = f2b(v.y); s.z = f2b(v.z); s.w = f2b(v.w);
            ((short4*)a.Vbf)[i] = s;
        } else if (bid < a.base_mask) {
            int i = (bid - a.base_bprep) * 256 + tid;
            float v;
            if (i < 2048) v = a.bq[i] * (FACT * LOG2E);
            else if (i < 4096) v = a.bk[i - 2048];
            else v = a.bvs[i - 4096];
            a.bqkv[i] = v;
        } else {
            int i = (bid - a.base_mask) * 256 + tid;
            a.maskadd[i] = a.mask[i] ? 0.f : -1e30f;
        }
        return;
    }
    int j = 0;
#pragma unroll
    for (int t = 1; t < 9; t++) j = (bid >= a.base[t]) ? t : j;
    const float* W = a.W[j];
    short* Wt = a.Wt[j];
    int K = a.K[j], N = a.N[j];
    float scale = a.scale[j];
    int local = bid - a.base[j];
    int nx = a.nx[j];
    int bx = local % nx, by = local / nx;
    __shared__ float t[32][33];
    int n0 = bx * 32, k0 = by * 32;
    int tx = tid & 31, ty = tid >> 5;
#pragma unroll
    for (int r = 0; r < 4; r++) t[ty + r * 8][tx] = W[(long)(k0 + ty + r * 8) * N + n0 + tx];
    __syncthreads();
#pragma unroll
    for (int r = 0; r < 4; r++) Wt[(long)(n0 + ty + r * 8) * K + k0 + tx] = f2b(t[tx][ty + r * 8] * scale);
}

__device__ __forceinline__ void stv(float* p, float v) { *p = v; }
__device__ __forceinline__ void stv(short* p, float v) { *p = f2b(v); }

// LayerNorm, output row stride ldo
template <typename OT>
__global__ __launch_bounds__(256) void ln_kernel(const float* __restrict__ x,
                                                 const float* __restrict__ g,
                                                 const float* __restrict__ b,
                                                 OT* __restrict__ y, int ldo) {
    int row = blockIdx.x;
    const float* xr = x + (long)row * Dh;
    OT* yr = y + (long)row * ldo;
    int tid = threadIdx.x;
    float v0 = xr[tid], v1 = xr[tid + 256];
    __shared__ float red[256];
    red[tid] = v0 + v1;
    __syncthreads();
    for (int o = 128; o > 0; o >>= 1) { if (tid < o) red[tid] += red[tid + o]; __syncthreads(); }
    float mean = red[0] * (1.0f / Dh);
    __syncthreads();
    float d0 = v0 - mean, d1 = v1 - mean;
    red[tid] = d0 * d0 + d1 * d1;
    __syncthreads();
    for (int o = 128; o > 0; o >>= 1) { if (tid < o) red[tid] += red[tid + o]; __syncthreads(); }
    float rstd = rsqrtf(red[0] * (1.0f / Dh) + 1e-5f);
    stv(&yr[tid], d0 * rstd * g[tid] + b[tid]);
    stv(&yr[tid + 256], d1 * rstd * g[tid + 256] + b[tid + 256]);
}

// ---- Vattn_t gather, vectorized ----
__global__ __launch_bounds__(256) void vattn_t8(const short* __restrict__ Hv, int ldh,
                                                const short* __restrict__ Vv,
                                                short* __restrict__ VaT) {
    int idx = blockIdx.x * 256 + threadIdx.x;
    int m = idx & 1023;
    int c = (idx >> 10) & 15;
    int s = idx >> 14;
    int b = s >> 4, h = s & 15;
    bf16x8 v;
    if (c < 4) {
        v = *(const bf16x8*)(Hv + ((long)b * Nseq + m) * ldh + h * 32 + c * 8);
    } else {
        int c3 = (c - 4) >> 2, dd = ((c - 4) & 3) * 8;
        v = *(const bf16x8*)(Vv + (((long)b * Nseq + m) * 3 + c3) * 512 + h * 32 + dd);
    }
    short* out = VaT + (long)s * 128 * 1024 + (long)c * 8 * 1024 + m;
    const short* vs = (const short*)&v;
#pragma unroll
    for (int e = 0; e < 8; e++) out[e * 1024] = vs[e];
}

// ---- scaler second half: ||V1|| over the 3-axis of Vp (float4) ----
__global__ __launch_bounds__(256) void scaler_norm(const float* __restrict__ Vp,
                                                   short* __restrict__ scaler) {
    int idx = blockIdx.x * 256 + threadIdx.x;
    int jj = (idx & 127) * 4;
    int row = idx >> 7;
    float4 ss = {0.f, 0.f, 0.f, 0.f};
#pragma unroll
    for (int c = 0; c < 3; c++) {
        float4 v = *(const float4*)(Vp + ((long)row * 3 + c) * 1024 + jj);
        ss.x += v.x * v.x; ss.y += v.y * v.y; ss.z += v.z * v.z; ss.w += v.w * v.w;
    }
    short4 o;
    o.x = f2b(sqrtf(ss.x)); o.y = f2b(sqrtf(ss.y));
    o.z = f2b(sqrtf(ss.z)); o.w = f2b(sqrtf(ss.w));
    *(short4*)(scaler + (long)row * 1024 + 512 + jj) = o;
}

// ---- final: H += s[:512]; V += s[512:] * V2 (float4) ----
__global__ __launch_bounds__(256) void final_k(float* __restrict__ outH,
                                               float* __restrict__ outV,
                                               const float* __restrict__ s,
                                               const float* __restrict__ Vp) {
    int idx = blockIdx.x * 256 + threadIdx.x;
    int jj = (idx & 127) * 4;
    int row = idx >> 7;
    float4 s1 = *(const float4*)(s + (long)row * 1024 + jj);
    float4 h = *(const float4*)(outH + (long)row * 512 + jj);
    h.x += s1.x; h.y += s1.y; h.z += s1.z; h.w += s1.w;
    *(float4*)(outH + (long)row * 512 + jj) = h;
    float4 vu = *(const float4*)(s + (long)row * 1024 + 512 + jj);
#pragma unroll
    for (int c = 0; c < 3; c++) {
        float4 v2 = *(const float4*)(Vp + ((long)row * 3 + c) * 1024 + 512 + jj);
        float* vp = outV + ((long)row * 3 + c) * 512 + jj;
        float4 vo = *(const float4*)vp;
        vo.x += vu.x * v2.x; vo.y += vu.y * v2.y;
        vo.z += vu.z * v2.z; vo.w += vu.w * v2.w;
        *(float4*)vp = vo;
    }
}

extern "C" void kernel_launch(void* const* d_in, const int* in_sizes, int n_in,
                              void* d_out, int out_size, void* d_ws, size_t ws_size,
                              hipStream_t stream) {
    const float* H    = (const float*)d_in[0];
    const float* V    = (const float*)d_in[1];
    const float* Dm   = (const float*)d_in[2];
    const float* rbf  = (const float*)d_in[3];
    const int*   mask = (const int*)d_in[4];
    const float* Wq   = (const float*)d_in[5];
    const float* bq   = (const float*)d_in[6];
    const float* Wk   = (const float*)d_in[7];
    const float* bk   = (const float*)d_in[8];
    const float* Wvs  = (const float*)d_in[9];
    const float* bvs  = (const float*)d_in[10];
    const float* Wvv  = (const float*)d_in[11];
    const float* Wo   = (const float*)d_in[12];
    const float* bo   = (const float*)d_in[13];
    const float* Wvo  = (const float*)d_in[14];
    const float* ln1g = (const float*)d_in[15];
    const float* ln1b = (const float*)d_in[16];
    const float* Wlv  = (const float*)d_in[17];
    const float* W1   = (const float*)d_in[18];
    const float* b1   = (const float*)d_in[19];
    const float* W2   = (const float*)d_in[20];
    const float* b2   = (const float*)d_in[21];
    const float* ln2g = (const float*)d_in[22];
    const float* ln2b = (const float*)d_in[23];

    char* wsb = (char*)d_ws;
    auto KB = [&](long kb) { return (void*)(wsb + kb * 1024l); };
    // weights (persistent through the call)
    short* WqkvT = (short*)KB(0);
    short* WvvT  = (short*)KB(4608);
    short* WoT   = (short*)KB(5120);
    short* WvoT  = (short*)KB(5632);
    short* WlvT  = (short*)KB(6144);
    short* W1T   = (short*)KB(7168);
    short* W2T   = (short*)KB(11264);
    float* bqkv  = (float*)KB(15360);
    // phase 1
    short* Hqkv = (short*)KB(15384);
    short* VvR  = (short*)KB(33816);
    short* VaT  = (short*)KB(39960);
    short* Hn   = (short*)KB(48152);
    short* Vbf  = (short*)KB(50200);
    short* Hres = (short*)KB(56344);   // contiguous with Vres
    short* Vres = (short*)KB(58392);
    float* maskadd = (float*)KB(64536);
    // phase 2 (reuses dead phase-1 regions)
    short* Vbf2   = (short*)KB(15384);
    float* Vp     = (float*)KB(21528);
    short* scaler = (short*)KB(46104);
    short* t1     = (short*)KB(50200);
    float* sbuf   = (float*)KB(58392);

    float* outH = (float*)d_out;
    float* outV = outH + (size_t)Bc * Nseq * Dh;

    // ---- single merged prep launch ----
    PrepJobs a;
    const float* srcs[9] = {Wq, Wk, Wvs, Wvv, Wo, Wvo, Wlv, W1, W2};
    short* dsts[9] = {WqkvT, WqkvT + 2048 * 512, WqkvT + 4096 * 512,
                      WvvT, WoT, WvoT, WlvT, W1T, W2T};
    int Ks[9] = {512, 512, 512, 512, 512, 512, 512, 1024, 2048};
    int Ns[9] = {2048, 2048, 512, 512, 512, 512, 1024, 2048, 1024};
    float scl[9] = {FACT * LOG2E, 1.f, 1.f, 1.f, 1.f, 1.f, 1.f, 1.f, 1.f};
    int base = 0;
    for (int j = 0; j < 9; j++) {
        a.W[j] = srcs[j]; a.Wt[j] = dsts[j];
        a.K[j] = Ks[j]; a.N[j] = Ns[j];
        a.nx[j] = Ns[j] / 32;
        a.scale[j] = scl[j];
        a.base[j] = base;
        base += (Ns[j] / 32) * (Ks[j] / 32);
    }
    a.base_convk = base;
    a.base_bprep = base + 3072;
    a.base_mask  = base + 3072 + 18;
    a.V = V; a.Vbf = Vbf;
    a.bq = bq; a.bk = bk; a.bvs = bvs; a.bqkv = bqkv;
    a.mask = mask; a.maskadd = maskadd;
    int prep_blocks = a.base_mask + 8;
    prep_k<<<prep_blocks, 256, 0, stream>>>(a);

    // LN1 -> bf16
    ln_kernel<short><<<2048, 256, 0, stream>>>(H, ln1g, ln1b, Hn, 512);
    // merged QKV + Vvv projection (flat 768-block grid)
    gemm_qkv_vvv<<<768, 256, 0, stream>>>(Hn, WqkvT, Vbf, WvvT, Hqkv, VvR, bqkv);
    vattn_t8<<<2048, 256, 0, stream>>>(Hqkv + 4096, 4608, VvR, VaT);

    // fused flash attention: 512 blocks x 256 threads (v5 structure)
    flash_attn<<<dim3(512), 256, 0, stream>>>(Hqkv, Hqkv + 2048, VaT, rbf, Dm, maskadd,
                                              Hres, Vres, 4608);

    // merged Wo + Wvo output projections (f32 into d_out; Wvo also emits bf16 Vbf2)
    gemm_out<<<dim3(4, 64), 256, 0, stream>>>(Hres, WoT, WvoT, outH, H, V, Vbf2, bo);
    // LN2 writes bf16 directly into scaler[:, :512]
    ln_kernel<short><<<2048, 256, 0, stream>>>(outH, ln2g, ln2b, scaler, 1024);
    gemm_bf16<<<dim3(8, 48, 1), 256, 0, stream>>>(Vbf2, 512, 0, WlvT, 512, 0, Vp, 1024, 0,
                                                  nullptr, nullptr, 0, 0, nullptr, 512, 0);
    scaler_norm<<<1024, 256, 0, stream>>>(Vp, scaler);
    gemm_bf16<<<dim3(16, 16, 1), 256, 0, stream>>>(scaler, 1024, 0, W1T, 1024, 0, t1, 2048, 0,
                                                   b1, nullptr, 0, 0, nullptr, 1024, 3);
    gemm_bf16<<<dim3(8, 16, 1), 256, 0, stream>>>(t1, 2048, 0, W2T, 2048, 0, sbuf, 1024, 0,
                                                  b2, nullptr, 0, 0, nullptr, 2048, 0);
    final_k<<<1024, 256, 0, stream>>>(outH, outV, sbuf, Vp);
}